// Round 3
// baseline (741.461 us; speedup 1.0000x reference)
//
#include <hip/hip_runtime.h>
#include <cmath>

// ---------------------------------------------------------------------------
// 6x (conv3x3+BN+ReLU) -> LSTM(4096->256) over S=64 -> tanh(linear).
// R9: convs L1..L5 ported to split-bf16 MFMA implicit-GEMM (hh+hl+lh, the
// 3-stream split proven at absmax 3e-8 in R8's GEMM). L0 (K=27) stays fp32.
// R10/R11 (FAILED): two attempts to make the 1024-thread fp32-matvec LSTM
// hold its 64 weight VGPRs failed -- launch_bounds and asm pins both lost to
// the allocator under 16-wave pressure (VGPR stayed 48-52); w_hh re-streamed
// 256KB/CU/step from L2 (~150GB/s per-CU = 1.6us/step = whole step time).
// Worse, all 16 batch-blocks re-read the SAME 1MB of w_hh (fp32 matvec can't
// amortize weights over batches).
// R12: LSTM rebuilt as per-step MFMA GEMM: gates(1024x16) = W_hh x h(256x16).
// 16 blocks x 256 thr (4 waves = 4 gates, j-tile of 16 per block). A-frags =
// split-bf16 weights, 64 VGPR/thread, loaded ONCE (launch_bounds(256,1): 4
// waves/CU, cap 512 -> zero allocator pressure, LICM holds them). Weight
// traffic/step: ZERO. h exchanged all-to-all via proven hpair tag-poll
// (per-step slots); B-frags built in LDS [b][k] bf16 hi/lo with +8 row pad
// (bank-uniform ds_read_b128). 24 MFMA/wave/step. xg prefetched before poll.
// ---------------------------------------------------------------------------

typedef __attribute__((ext_vector_type(8))) __bf16 bf16x8;
typedef __attribute__((ext_vector_type(4))) float f32x4;

__device__ __forceinline__ float sigmoidf_(float x) { return 1.f / (1.f + expf(-x)); }

__device__ __forceinline__ float fsig_(float x) {
  return __builtin_amdgcn_rcpf(1.f + __expf(-x));
}
__device__ __forceinline__ float ftanh_(float x) {
  float xc = fminf(fmaxf(x, -15.f), 15.f);
  float e = __expf(2.f * xc);
  return (e - 1.f) * __builtin_amdgcn_rcpf(e + 1.f);
}

__device__ __forceinline__ unsigned short f2bf(float f) {   // RNE
  unsigned u = __float_as_uint(f);
  unsigned r = (u + 0x7fffu + ((u >> 16) & 1u)) >> 16;
  return (unsigned short)r;
}
__device__ __forceinline__ float bf2f(unsigned short h) {
  return __uint_as_float(((unsigned)h) << 16);
}

// ---------------- fold BN into conv weights (fp32 path + bias) ----------
struct FoldPack {
  const float *w[6], *g[6], *b[6], *m[6], *v[6];
  float *wf[6], *bias[6];
  int oc[6], ic[6];
};

__global__ __launch_bounds__(256) void fold_all(FoldPack p) {
  const int layer = blockIdx.y;
  const int OC = p.oc[layer], IC = p.ic[layer];
  const int total = OC * IC * 9;
  const float* w = p.w[layer];
  float* wf = p.wf[layer];
  for (int i = blockIdx.x * 256 + threadIdx.x; i < total; i += gridDim.x * 256) {
    int oc = i / (IC * 9);
    int r  = i % (IC * 9);
    int ic = r / 9;
    int k  = r % 9;
    int ky = k / 3, kx = k % 3;
    float inv = p.g[layer][oc] / sqrtf(p.v[layer][oc] + 1e-5f);
    wf[(((ic * 3 + ky) * OC) + oc) * 4 + kx] = w[i] * inv;
  }
  if (blockIdx.x == 0) {
    int i = threadIdx.x;
    if (i < OC) {
      float inv = p.g[layer][i] / sqrtf(p.v[layer][i] + 1e-5f);
      p.bias[layer][i] = p.b[layer][i] - p.m[layer][i] * inv;
    }
  }
}

// ---------------- pack BN-folded weights into MFMA A-frag layout ----------
struct PackPack {
  const float *w[5], *g[5], *v[5];
  unsigned short *wh[5], *wl[5];
  int ic[5], oc[5], kg[5], kreal[5];
};

__global__ __launch_bounds__(256) void pack_w(PackPack p) {
  const int layer = blockIdx.y;
  const int IC = p.ic[layer], KG = p.kg[layer], K = p.kreal[layer];
  const int MT = p.oc[layer] / 16;
  const int total = MT * KG * 512;
  for (int i = blockIdx.x * 256 + threadIdx.x; i < total; i += gridDim.x * 256) {
    int j = i & 7;
    int lane = (i >> 3) & 63;
    int gmt = i >> 9;               // = mt*KG + g
    int m = (gmt / KG) * 16 + (lane & 15);
    int k = 32 * (gmt % KG) + 8 * (lane >> 4) + j;
    float val = 0.f;
    if (k < K) {
      int tap = k / IC, ic = k % IC;
      int ky = tap / 3, kx = tap % 3;
      float inv = p.g[layer][m] / sqrtf(p.v[layer][m] + 1e-5f);
      val = p.w[layer][((m * IC + ic) * 3 + ky) * 3 + kx] * inv;
    }
    unsigned short h = f2bf(val);
    p.wh[layer][i] = h;
    p.wl[layer][i] = f2bf(val - bf2f(h));
  }
}

// ---------------- pack w_hh into LSTM MFMA A-frag layout ----------------
// i = (((bk*4+gate)*8+g)*64+lane)*8+e ; j = bk*16+(lane&15),
// k = 32g + 8*(lane>>4) + e ; src row = gate*256+j. bf16 hi + lo.
__global__ __launch_bounds__(256) void pack_whh(
    const float* __restrict__ w_hh, unsigned short* __restrict__ ph,
    unsigned short* __restrict__ pl)
{
  int i = blockIdx.x * 256 + threadIdx.x;   // 0..262143
  int e = i & 7;
  int lane = (i >> 3) & 63;
  int g = (i >> 9) & 7;
  int gw = i >> 12;            // bk*4 + gate
  int gate = gw & 3;
  int bk = gw >> 2;
  int j = bk * 16 + (lane & 15);
  int k = 32 * g + 8 * (lane >> 4) + e;
  float val = w_hh[((size_t)(gate * 256 + j)) * 256 + k];
  unsigned short h = f2bf(val);
  ph[i] = h;
  pl[i] = f2bf(val - bf2f(h));
}

// ---------------- fp32 direct conv (L0 only: IC=3, K=27) ----------------
template<int IC, int OC, int IH, int IW, int STRIDE, int TPOS, int SPLITY,
         int ICS, int MINW>
__global__ __launch_bounds__(256, MINW) void conv_bn_relu(
    const float* __restrict__ in, const float* __restrict__ wf,
    const float* __restrict__ bias, float* __restrict__ out)
{
  constexpr int OH = IH / STRIDE, OW = IW / STRIDE;
  constexpr int OHB = OH / SPLITY;
  constexpr int RIH = (SPLITY == 1) ? (IH + 2) : ((OHB - 1) * STRIDE + 3);
  constexpr int PIW = IW + 4;
  constexpr int PLANE = RIH * PIW;
  constexpr int NPOS = OHB * OW;
  constexpr int WPOS = NPOS / TPOS;
  constexpr int SLOT = WPOS * ICS;
  constexpr int GROUPS = 256 / SLOT;
  constexpr int TOC = OC / GROUPS;
  constexpr int CH = IC / ICS;
  constexpr int SPAN = (TPOS - 1) * STRIDE + 3;
  constexpr int NW = (SPAN + 3) / 4;
  constexpr int XSLOTS = OW / TPOS;
  static_assert(SLOT % 64 == 0 && GROUPS * SLOT == 256 && GROUPS * TOC == OC, "tiling");

  __shared__ float s_in[IC * PLANE];

  const int tid = threadIdx.x;
  const int n     = (SPLITY == 1) ? blockIdx.x : blockIdx.x / SPLITY;
  const int split = (SPLITY == 1) ? 0 : blockIdx.x % SPLITY;
  const int ry0 = split * OHB;
  const int r0  = ry0 * STRIDE - 1;

  for (int i = tid; i < IC * PLANE / 4; i += 256)
    ((float4*)s_in)[i] = float4{0.f, 0.f, 0.f, 0.f};
  __syncthreads();

  constexpr int ROWF4 = IW / 4;
  constexpr int NSTG = IC * RIH * ROWF4;
  for (int i = tid; i < NSTG; i += 256) {
    int rw  = i % ROWF4;
    int t   = i / ROWF4;
    int row = t % RIH;
    int ic  = t / RIH;
    int giy = r0 + row;
    if (giy >= 0 && giy < IH) {
      float4 v = *(const float4*)(in + ((size_t)(n * IC + ic) * IH + giy) * IW + rw * 4);
      float* dst = &s_in[(ic * RIH + row) * PIW + 1 + rw * 4];
      dst[0] = v.x; dst[1] = v.y; dst[2] = v.z; dst[3] = v.w;
    }
  }
  __syncthreads();

  const int group  = tid / SLOT;
  const int sl     = tid % SLOT;
  const int icq    = sl / WPOS;
  const int worker = sl % WPOS;
  const int oy  = worker / XSLOTS;
  const int ox0 = (worker % XSLOTS) * TPOS;
  const int xb  = ox0 * STRIDE;

  const int oc0u = __builtin_amdgcn_readfirstlane(group * TOC);
  const float4* wg = (const float4*)wf + oc0u;

  float acc[TOC][TPOS];
  #pragma unroll
  for (int a = 0; a < TOC; ++a)
    #pragma unroll
    for (int p = 0; p < TPOS; ++p) acc[a][p] = 0.f;

  for (int icl = 0; icl < CH; ++icl) {
    const int ic = icq * CH + icl;
    const float* sI = &s_in[ic * PLANE];
    #pragma unroll
    for (int ky = 0; ky < 3; ++ky) {
      float row[NW * 4];
      {
        const float4* rp = (const float4*)&sI[(oy * STRIDE + ky) * PIW + xb];
        #pragma unroll
        for (int w = 0; w < NW; ++w) {
          float4 t4 = rp[w];
          row[4*w+0] = t4.x; row[4*w+1] = t4.y;
          row[4*w+2] = t4.z; row[4*w+3] = t4.w;
        }
      }
      const float4* wrow = wg + (ic * 3 + ky) * OC;
      #pragma unroll
      for (int oc = 0; oc < TOC; ++oc) {
        float4 w4 = wrow[oc];
        #pragma unroll
        for (int p = 0; p < TPOS; ++p)
          acc[oc][p] = fmaf(row[p * STRIDE + 0], w4.x,
                       fmaf(row[p * STRIDE + 1], w4.y,
                       fmaf(row[p * STRIDE + 2], w4.z, acc[oc][p])));
      }
    }
  }

  #pragma unroll
  for (int d = WPOS; d < SLOT; d <<= 1)
    #pragma unroll
    for (int oc = 0; oc < TOC; ++oc)
      #pragma unroll
      for (int p = 0; p < TPOS; ++p)
        acc[oc][p] += __shfl_xor(acc[oc][p], d);

  if (icq == 0) {
    float* outN = out + (size_t)n * (OC * OH * OW);
    #pragma unroll
    for (int oc = 0; oc < TOC; ++oc) {
      const float bb = bias[oc0u + oc];
      float* op = outN + ((size_t)(oc0u + oc) * OH + (ry0 + oy)) * OW + ox0;
      #pragma unroll
      for (int vq = 0; vq < TPOS / 4; ++vq) {
        float4 val;
        val.x = fmaxf(acc[oc][vq*4+0] + bb, 0.f);
        val.y = fmaxf(acc[oc][vq*4+1] + bb, 0.f);
        val.z = fmaxf(acc[oc][vq*4+2] + bb, 0.f);
        val.w = fmaxf(acc[oc][vq*4+3] + bb, 0.f);
        *(float4*)(op + vq * 4) = val;
      }
    }
  }
}

// ---------------- MFMA implicit-GEMM conv (L1..L5) ----------------
template<int IC, int OC, int IH, int IW, int STRIDE, int SPLITY, int KG, int ZROW>
__global__ __launch_bounds__(256, 2) void conv_mfma(
    const float* __restrict__ in, const unsigned short* __restrict__ Ah,
    const unsigned short* __restrict__ Al, const float* __restrict__ bias,
    float* __restrict__ out)
{
  constexpr int OH = IH / STRIDE, OW = IW / STRIDE;
  constexpr int OHB = OH / SPLITY;
  constexpr int N = OHB * OW;
  constexpr int NT = N / 16;
  constexpr int NTW = NT / 4;              // n-tiles per wave
  constexpr int MT = OC / 16;
  constexpr int ICP = IC + 8;              // bank-skew pad (2-way worst, stride1)
  constexpr int PW = IW + 3;
  constexpr int PH = (OHB - 1) * STRIDE + 3 + ZROW;
  constexpr int SZ = ((PH * PW * ICP + 7) / 8) * 8;
  static_assert(NT % 4 == 0, "nt");

  __shared__ unsigned short s_h[SZ];
  __shared__ unsigned short s_l[SZ];

  const int tid = threadIdx.x;
  const int n     = (SPLITY == 1) ? blockIdx.x : blockIdx.x / SPLITY;
  const int split = (SPLITY == 1) ? 0 : blockIdx.x % SPLITY;
  const int y0 = split * OHB;
  const int r0 = y0 * STRIDE - 1;

  // zero both planes (halo + K-pad rows must be finite-zero)
  for (int i = tid * 8; i < SZ; i += 2048) {
    *(int4*)&s_h[i] = int4{0, 0, 0, 0};
    *(int4*)&s_l[i] = int4{0, 0, 0, 0};
  }
  __syncthreads();

  // stage NCHW fp32 -> NHWC bf16 hi/lo (rows clipped at runtime)
  constexpr int ROWF4 = IW / 4;
  for (int i = tid; i < IC * PH * ROWF4; i += 256) {
    int rw  = i % ROWF4;
    int t   = i / ROWF4;
    int row = t % PH;
    int ic  = t / PH;
    int giy = r0 + row;
    if (giy >= 0 && giy < IH) {
      float4 v = *(const float4*)(in + ((size_t)(n * IC + ic) * IH + giy) * IW + rw * 4);
      int base = (row * PW + rw * 4 + 1) * ICP + ic;
      float vv[4] = {v.x, v.y, v.z, v.w};
      #pragma unroll
      for (int e = 0; e < 4; ++e) {
        unsigned short h = f2bf(vv[e]);
        s_h[base + e * ICP] = h;
        s_l[base + e * ICP] = f2bf(vv[e] - bf2f(h));
      }
    }
  }
  __syncthreads();

  const int wave = tid >> 6;
  const int lane = tid & 63;
  const int l16  = lane & 15;
  const int quad = lane >> 4;

  f32x4 acc[MT][NTW];
  #pragma unroll
  for (int mt = 0; mt < MT; ++mt)
    #pragma unroll
    for (int nt = 0; nt < NTW; ++nt) acc[mt][nt] = f32x4{0.f, 0.f, 0.f, 0.f};

  for (int g = 0; g < KG; ++g) {
    const int k0 = 32 * g + 8 * quad;
    const int tap = k0 / IC;
    const int ic0 = k0 % IC;
    const int ky = tap / 3;
    const int kx = tap - ky * 3;
    bf16x8 afh[MT], afl[MT];
    #pragma unroll
    for (int mt = 0; mt < MT; ++mt) {
      size_t wo = ((size_t)(mt * KG + g) * 64 + lane) * 8;
      afh[mt] = __builtin_bit_cast(bf16x8, *(const int4*)(Ah + wo));
      afl[mt] = __builtin_bit_cast(bf16x8, *(const int4*)(Al + wo));
    }
    #pragma unroll
    for (int nt = 0; nt < NTW; ++nt) {
      int p = (wave * NTW + nt) * 16 + l16;
      int py = p / OW, px = p % OW;
      int addr = ((py * STRIDE + ky) * PW + px * STRIDE + kx) * ICP + ic0;
      bf16x8 bh = __builtin_bit_cast(bf16x8, *(const int4*)&s_h[addr]);
      bf16x8 bl = __builtin_bit_cast(bf16x8, *(const int4*)&s_l[addr]);
      #pragma unroll
      for (int mt = 0; mt < MT; ++mt) {
        acc[mt][nt] = __builtin_amdgcn_mfma_f32_16x16x32_bf16(afh[mt], bh, acc[mt][nt], 0, 0, 0);
        acc[mt][nt] = __builtin_amdgcn_mfma_f32_16x16x32_bf16(afh[mt], bl, acc[mt][nt], 0, 0, 0);
        acc[mt][nt] = __builtin_amdgcn_mfma_f32_16x16x32_bf16(afl[mt], bh, acc[mt][nt], 0, 0, 0);
      }
    }
  }

  // epilogue: bias + relu, NCHW store (col=pos coalesced per oc-row)
  #pragma unroll
  for (int mt = 0; mt < MT; ++mt)
    #pragma unroll
    for (int nt = 0; nt < NTW; ++nt) {
      int p = (wave * NTW + nt) * 16 + l16;
      int py = p / OW, px = p % OW;
      #pragma unroll
      for (int r = 0; r < 4; ++r) {
        int oc = mt * 16 + quad * 4 + r;
        float v = acc[mt][nt][r] + bias[oc];
        out[((size_t)(n * OC + oc) * OH + y0 + py) * OW + px] = fmaxf(v, 0.f);
      }
    }
}

// ---------------- bf16 hi/lo split prepass (GEMM inputs) ----------------
__global__ __launch_bounds__(256) void split_a(
    const float* __restrict__ feats, unsigned short* __restrict__ ah,
    unsigned short* __restrict__ al)
{
  int i4 = blockIdx.x * 256 + threadIdx.x;
  int e = i4 * 4;
  int n = e >> 12;
  int k = e & 4095;
  int r = (n & 63) * 16 + (n >> 6);
  float4 v = ((const float4*)feats)[i4];
  ushort4 h, l;
  h.x = f2bf(v.x); l.x = f2bf(v.x - bf2f(h.x));
  h.y = f2bf(v.y); l.y = f2bf(v.y - bf2f(h.y));
  h.z = f2bf(v.z); l.z = f2bf(v.z - bf2f(h.z));
  h.w = f2bf(v.w); l.w = f2bf(v.w - bf2f(h.w));
  *(ushort4*)(ah + (size_t)r * 4096 + k) = h;
  *(ushort4*)(al + (size_t)r * 4096 + k) = l;
}

__global__ __launch_bounds__(256) void split_b(
    const float* __restrict__ w_ih, unsigned short* __restrict__ bh,
    unsigned short* __restrict__ bl)
{
  int i4 = blockIdx.x * 256 + threadIdx.x;
  float4 v = ((const float4*)w_ih)[i4];
  ushort4 h, l;
  h.x = f2bf(v.x); l.x = f2bf(v.x - bf2f(h.x));
  h.y = f2bf(v.y); l.y = f2bf(v.y - bf2f(h.y));
  h.z = f2bf(v.z); l.z = f2bf(v.z - bf2f(h.z));
  h.w = f2bf(v.w); l.w = f2bf(v.w - bf2f(h.w));
  ((ushort4*)bh)[i4] = h;
  ((ushort4*)bl)[i4] = l;
}

// ---------------- Xg partials: bf16 split-MFMA GEMM ----------------
__global__ __launch_bounds__(256) void mfma_xg(
    const unsigned short* __restrict__ Ah, const unsigned short* __restrict__ Al,
    const unsigned short* __restrict__ Bh, const unsigned short* __restrict__ Bl,
    float* __restrict__ part)
{
  __shared__ unsigned short s_ah[128 * 40];
  __shared__ unsigned short s_al[128 * 40];
  __shared__ unsigned short s_bh[128 * 40];
  __shared__ unsigned short s_bl[128 * 40];

  const int tid = threadIdx.x;
  const int col0 = blockIdx.x * 128;
  const int row0 = blockIdx.y * 128;
  const int kbase = blockIdx.z * 512;
  float* outp = part + (size_t)blockIdx.z * 1048576;

  const int wave = tid >> 6;
  const int lane = tid & 63;
  const int wr = wave >> 1, wc = wave & 1;
  const int quad = lane >> 4;
  const int l16 = lane & 15;

  f32x4 acc[4][4];
  #pragma unroll
  for (int i = 0; i < 4; ++i)
    #pragma unroll
    for (int j = 0; j < 4; ++j) acc[i][j] = f32x4{0.f, 0.f, 0.f, 0.f};

  for (int step = 0; step < 16; ++step) {
    const int koff = kbase + step * 32;
    #pragma unroll
    for (int c = tid; c < 512; c += 256) {
      int row = c >> 2, kc = (c & 3) * 8;
      int4 va = *(const int4*)(Ah + (size_t)(row0 + row) * 4096 + koff + kc);
      int4 vb = *(const int4*)(Al + (size_t)(row0 + row) * 4096 + koff + kc);
      int4 vc = *(const int4*)(Bh + (size_t)(col0 + row) * 4096 + koff + kc);
      int4 vd = *(const int4*)(Bl + (size_t)(col0 + row) * 4096 + koff + kc);
      *(int4*)&s_ah[row * 40 + kc] = va;
      *(int4*)&s_al[row * 40 + kc] = vb;
      *(int4*)&s_bh[row * 40 + kc] = vc;
      *(int4*)&s_bl[row * 40 + kc] = vd;
    }
    __syncthreads();

    bf16x8 arh[4], arl[4];
    #pragma unroll
    for (int i = 0; i < 4; ++i) {
      int m = wr * 64 + i * 16 + l16;
      arh[i] = __builtin_bit_cast(bf16x8, *(const int4*)&s_ah[m * 40 + quad * 8]);
      arl[i] = __builtin_bit_cast(bf16x8, *(const int4*)&s_al[m * 40 + quad * 8]);
    }
    #pragma unroll
    for (int j = 0; j < 4; ++j) {
      int nn = wc * 64 + j * 16 + l16;
      bf16x8 brh = __builtin_bit_cast(bf16x8, *(const int4*)&s_bh[nn * 40 + quad * 8]);
      bf16x8 brl = __builtin_bit_cast(bf16x8, *(const int4*)&s_bl[nn * 40 + quad * 8]);
      #pragma unroll
      for (int i = 0; i < 4; ++i) {
        acc[i][j] = __builtin_amdgcn_mfma_f32_16x16x32_bf16(arh[i], brh, acc[i][j], 0, 0, 0);
        acc[i][j] = __builtin_amdgcn_mfma_f32_16x16x32_bf16(arh[i], brl, acc[i][j], 0, 0, 0);
        acc[i][j] = __builtin_amdgcn_mfma_f32_16x16x32_bf16(arl[i], brh, acc[i][j], 0, 0, 0);
      }
    }
    __syncthreads();
  }

  #pragma unroll
  for (int i = 0; i < 4; ++i)
    #pragma unroll
    for (int j = 0; j < 4; ++j) {
      int row = row0 + wr * 64 + i * 16 + quad * 4;
      int col = col0 + wc * 64 + j * 16 + l16;
      #pragma unroll
      for (int r = 0; r < 4; ++r)
        outp[(size_t)(row + r) * 1024 + col] = acc[i][j][r];
    }
}

// xg = sum_z p[z] + (b_ih + b_hh)
__global__ __launch_bounds__(256) void reduce_xg(
    const float* __restrict__ p, const float* __restrict__ b_ih,
    const float* __restrict__ b_hh, float* __restrict__ xg)
{
  int i = blockIdx.x * 256 + threadIdx.x;
  float4 s = {0.f, 0.f, 0.f, 0.f};
  #pragma unroll
  for (int z = 0; z < 8; ++z) {
    float4 a = ((const float4*)p)[(size_t)z * 262144 + i];
    s.x += a.x; s.y += a.y; s.z += a.z; s.w += a.w;
  }
  int cb = i & 255;
  float4 bi = ((const float4*)b_ih)[cb];
  float4 bh = ((const float4*)b_hh)[cb];
  float4 o;
  o.x = s.x + bi.x + bh.x;
  o.y = s.y + bi.y + bh.y;
  o.z = s.z + bi.z + bh.z;
  o.w = s.w + bi.w + bh.w;
  ((float4*)xg)[i] = o;
}

// ---------------- persistent MFMA LSTM recurrence ----------------
// 16 blocks x 256 thr. Block bk owns j in [16bk,16bk+16); wave = gate.
// Per step: gates(16j x 16b) = W_hh-tile x h(256 x 16b) via split-bf16
// 16x16x32 MFMA (hh+hl+lh). A-frags (weights): 8 ksteps x hi/lo = 64 VGPR,
// loaded ONCE before the loop (4 waves/CU, launch_bounds(256,1) -> cap 512,
// no allocator pressure -> LICM keeps them resident; kills the 256KB/CU/step
// L2 weight stream that floored R9-R11 at ~1.6us/step). h(s-1) exchanged
// all-to-all via hpair tag-poll (per-step slots, tag=s): thread t polls
// j=t for all 16 b (16 pipelined loads, then per-elem retry), converts to
// bf16 hi/lo into LDS [b][264] (+8 pad -> bank-uniform ds_read_b128 B-frags).
// C layout (proven): row j = quad*4+r, col b = l16 -> s_g LDS; combine phase
// (cb=tid>>4, cj=tid&15) adds prefetched xg, runs gates, writes hs + tagged
// hpair. 2 barriers/step. Step chain: poll ~0.35us + frags/mfma ~0.15 +
// combine ~0.15 => ~0.6-0.8us/step vs 1.58 before.
__global__ __launch_bounds__(256, 1) void lstm_mfma(
    const float* __restrict__ xg, const unsigned short* __restrict__ Wh,
    const unsigned short* __restrict__ Wl, float* __restrict__ hs,
    unsigned long long* __restrict__ hpair)
{
  const int bk = blockIdx.x;            // j-tile
  const int tid = threadIdx.x;
  const int wave = tid >> 6;            // = gate
  const int lane = tid & 63;
  const int l16 = lane & 15;
  const int quad = lane >> 4;

  // A-frags: weights for (gate=wave, j-tile bk), 8 k-steps, hi+lo planes.
  bf16x8 ah[8], al[8];
  #pragma unroll
  for (int g = 0; g < 8; ++g) {
    size_t o = (((size_t)(bk * 4 + wave) * 8 + g) * 64 + lane) * 8;
    ah[g] = __builtin_bit_cast(bf16x8, *(const int4*)(Wh + o));
    al[g] = __builtin_bit_cast(bf16x8, *(const int4*)(Wl + o));
  }

  __shared__ unsigned short s_hh[16][264];   // [b][k], +8 pad (bank-uniform)
  __shared__ unsigned short s_hl[16][264];
  __shared__ float s_g[4][16][17];           // [gate][j][b], +1 pad

  const int cb = tid >> 4;        // combine identity: batch
  const int cj = tid & 15;        // local j
  const int jglob = bk * 16 + cj;
  float c_reg = 0.f;

  for (int s = 0; s < 64; ++s) {
    // prefetch xg (independent of h -> hides under poll)
    const float* xp = xg + (size_t)(s * 16 + cb) * 1024 + jglob;
    float xv0 = xp[0];
    float xv1 = xp[256];
    float xv2 = xp[512];
    float xv3 = xp[768];

    f32x4 acc = f32x4{0.f, 0.f, 0.f, 0.f};
    if (s > 0) {
      // poll h(s-1): thread t owns j=t, all 16 batches. Issue all 16 loads
      // first (pipelined), then validate/retry per element.
      const unsigned long long* src = hpair + (size_t)(s - 1) * 4096 + tid;
      unsigned long long pv[16];
      #pragma unroll
      for (int i = 0; i < 16; ++i)
        pv[i] = __hip_atomic_load(src + i * 256, __ATOMIC_RELAXED,
                                  __HIP_MEMORY_SCOPE_AGENT);
      #pragma unroll
      for (int i = 0; i < 16; ++i) {
        while ((unsigned)(pv[i] >> 32) != (unsigned)s)
          pv[i] = __hip_atomic_load(src + i * 256, __ATOMIC_RELAXED,
                                    __HIP_MEMORY_SCOPE_AGENT);
        float hv = __uint_as_float((unsigned)pv[i]);
        unsigned short hh = f2bf(hv);
        s_hh[i][tid] = hh;
        s_hl[i][tid] = f2bf(hv - bf2f(hh));
      }
      __syncthreads();

      #pragma unroll
      for (int g = 0; g < 8; ++g) {
        const int off = 32 * g + quad * 8;
        bf16x8 bh = __builtin_bit_cast(bf16x8, *(const int4*)&s_hh[l16][off]);
        bf16x8 bl = __builtin_bit_cast(bf16x8, *(const int4*)&s_hl[l16][off]);
        acc = __builtin_amdgcn_mfma_f32_16x16x32_bf16(ah[g], bh, acc, 0, 0, 0);
        acc = __builtin_amdgcn_mfma_f32_16x16x32_bf16(ah[g], bl, acc, 0, 0, 0);
        acc = __builtin_amdgcn_mfma_f32_16x16x32_bf16(al[g], bh, acc, 0, 0, 0);
      }
    }
    // C: row(j) = quad*4+r, col(b) = l16  (proven layout)
    #pragma unroll
    for (int r = 0; r < 4; ++r)
      s_g[wave][quad * 4 + r][l16] = acc[r];
    __syncthreads();

    // combine: thread (cb, cj)
    float gi = s_g[0][cj][cb] + xv0;
    float gf = s_g[1][cj][cb] + xv1;
    float gg = s_g[2][cj][cb] + xv2;
    float go = s_g[3][cj][cb] + xv3;
    float cn = fsig_(gf) * c_reg + fsig_(gi) * ftanh_(gg);
    c_reg = cn;
    float hv = fsig_(go) * ftanh_(cn);
    hs[(size_t)s * 4096 + cb * 256 + jglob] = hv;
    unsigned long long opv =
        ((unsigned long long)(unsigned)(s + 1) << 32) | __float_as_uint(hv);
    __hip_atomic_store(hpair + (size_t)s * 4096 + cb * 256 + jglob, opv,
                       __ATOMIC_RELAXED, __HIP_MEMORY_SCOPE_AGENT);
    // No trailing barrier needed: next step's s_hh writes are fenced by the
    // post-poll barrier; next step's s_g writes come after it too.
  }
}

// ---------------- classifier head ----------------
__global__ __launch_bounds__(64) void cls_kernel(
    const float* __restrict__ hs, const float* __restrict__ cw,
    const float* __restrict__ cb, float* __restrict__ out)
{
  const int id = blockIdx.x;
  const int b = id / 53;
  const int t = id % 53;
  const int s = 11 + t;
  const int lane = threadIdx.x;
  float4 hv = ((const float4*)(hs + (size_t)s * 4096 + b * 256))[lane];
  float4 wv = ((const float4*)cw)[lane];
  float p = hv.x * wv.x + hv.y * wv.y + hv.z * wv.z + hv.w * wv.w;
  #pragma unroll
  for (int off = 32; off >= 1; off >>= 1) p += __shfl_xor(p, off);
  if (lane == 0) out[id] = tanhf(p + cb[0]);
}

// ---------------------------------------------------------------------------
extern "C" void kernel_launch(void* const* d_in, const int* in_sizes, int n_in,
                              void* d_out, int out_size, void* d_ws, size_t ws_size,
                              hipStream_t stream)
{
  (void)in_sizes; (void)n_in; (void)out_size; (void)ws_size;
  const float* imgs = (const float*)d_in[0];
  const float* w_ih  = (const float*)d_in[31];
  const float* w_hh  = (const float*)d_in[32];
  const float* b_ih  = (const float*)d_in[33];
  const float* b_hh  = (const float*)d_in[34];
  const float* cls_w = (const float*)d_in[35];
  const float* cls_b = (const float*)d_in[36];
  float* out = (float*)d_out;

  float* ws   = (float*)d_ws;
  float* actA = ws;
  float* actB = actA + 16777216;
  float* xg   = actB + 16777216;
  float* hs   = xg + 1048576;
  unsigned long long* hpair = (unsigned long long*)(hs + 262144);
  float* wfp  = hs + 262144 + 524288;
  static const int ocs[6] = {16, 16, 32, 32, 64, 64};
  static const int ics[6] = {3, 16, 16, 32, 32, 64};
  float* wf[6];
  size_t off = 0;
  for (int i = 0; i < 6; ++i) { wf[i] = wfp + off; off += (size_t)ocs[i] * ics[i] * 12; }
  float* biasp = wfp + off;
  float* bias[6];
  for (int i = 0; i < 6; ++i) bias[i] = biasp + i * 64;

  // packed MFMA weights (L1..L5): sizes MT*KG*512 ushorts per plane
  static const int psz[5] = {2560, 5120, 9216, 18432, 36864};
  unsigned short* WH = (unsigned short*)(biasp + 6 * 64);
  unsigned short* WL = WH + 72192;
  unsigned short *wh[5], *wl[5];
  {
    int o = 0;
    for (int i = 0; i < 5; ++i) { wh[i] = WH + o; wl[i] = WL + o; o += psz[i]; }
  }

  float* partials = actA;       // reused post-conv
  unsigned short* Ah = (unsigned short*)(actA + 8388608);
  unsigned short* Al = Ah + 4194304;
  unsigned short* Bh = Al + 4194304;
  unsigned short* Bl = Bh + 4194304;

  // packed LSTM weights: carved from actB, which is dead after split_a.
  // pack_whh is launched AFTER split_a (same stream -> serialized).
  unsigned short* WHH_H = (unsigned short*)actB;
  unsigned short* WHH_L = WHH_H + 262144;

  FoldPack fp;
  for (int i = 0; i < 6; ++i) {
    fp.w[i] = (const float*)d_in[1 + 5*i];
    fp.g[i] = (const float*)d_in[2 + 5*i];
    fp.b[i] = (const float*)d_in[3 + 5*i];
    fp.m[i] = (const float*)d_in[4 + 5*i];
    fp.v[i] = (const float*)d_in[5 + 5*i];
    fp.wf[i] = wf[i];
    fp.bias[i] = bias[i];
    fp.oc[i] = ocs[i];
    fp.ic[i] = ics[i];
  }
  fold_all<<<dim3(8, 6), 256, 0, stream>>>(fp);

  PackPack pp;
  static const int kgs[5] = {5, 5, 9, 9, 18};
  static const int krs[5] = {144, 144, 288, 288, 576};
  for (int i = 0; i < 5; ++i) {
    pp.w[i] = (const float*)d_in[1 + 5*(i+1)];
    pp.g[i] = (const float*)d_in[2 + 5*(i+1)];
    pp.v[i] = (const float*)d_in[5 + 5*(i+1)];
    pp.wh[i] = wh[i];
    pp.wl[i] = wl[i];
    pp.ic[i] = ics[i+1];
    pp.oc[i] = ocs[i+1];
    pp.kg[i] = kgs[i];
    pp.kreal[i] = krs[i];
  }
  pack_w<<<dim3(36, 5), 256, 0, stream>>>(pp);

  // L0 fp32 direct conv
  conv_bn_relu<3, 16, 64, 64, 2, 4, 2, 1, 4><<<2048, 256, 0, stream>>>(imgs, wf[0], bias[0], actA);
  //            IC  OC  IH  IW  S SPL KG ZR
  conv_mfma<16, 16, 32, 32, 1, 4, 5, 1><<<4096, 256, 0, stream>>>(actA, wh[0], wl[0], bias[1], actB);
  conv_mfma<16, 32, 32, 32, 2, 4, 5, 1><<<4096, 256, 0, stream>>>(actB, wh[1], wl[1], bias[2], actA);
  conv_mfma<32, 32, 16, 16, 1, 1, 9, 0><<<1024, 256, 0, stream>>>(actA, wh[2], wl[2], bias[3], actB);
  conv_mfma<32, 64, 16, 16, 2, 1, 9, 0><<<1024, 256, 0, stream>>>(actB, wh[3], wl[3], bias[4], actA);
  conv_mfma<64, 64,  8,  8, 1, 1, 18, 0><<<1024, 256, 0, stream>>>(actA, wh[4], wl[4], bias[5], actB);

  split_a<<<4096, 256, 0, stream>>>(actB, Ah, Al);
  split_b<<<4096, 256, 0, stream>>>(w_ih, Bh, Bl);
  pack_whh<<<1024, 256, 0, stream>>>(w_hh, WHH_H, WHH_L);
  mfma_xg<<<dim3(8, 8, 8), 256, 0, stream>>>(Ah, Al, Bh, Bl, partials);
  reduce_xg<<<1024, 256, 0, stream>>>(partials, b_ih, b_hh, xg);
  lstm_mfma<<<16, 256, 0, stream>>>(xg, WHH_H, WHH_L, hs, hpair);
  cls_kernel<<<848, 64, 0, stream>>>(hs, cls_w, cls_b, out);
}

// Round 4
// 488.192 us; speedup vs baseline: 1.5188x; 1.5188x over previous
//
#include <hip/hip_runtime.h>
#include <cmath>

// ---------------------------------------------------------------------------
// 6x (conv3x3+BN+ReLU) -> LSTM(4096->256) over S=64 -> tanh(linear).
// R9: convs L1..L5 ported to split-bf16 MFMA implicit-GEMM (hh+hl+lh, proven
// absmax 3e-8). L0 (K=27) stays fp32.
// R10/R11 (FAILED): launch_bounds(1024,4) + asm pin did NOT hold wv[16] in
// VGPRs -- the 2nd launch_bounds arg is only a MIN waves/EU; the allocator
// still maximized occupancy (8 waves/EU -> <=64 VGPR) and spilled/remat'd,
// re-streaming w_hh 256KB/CU/step from L2 (~1.1us/step of the 1.58us step).
// R12 (FAILED, 356us): MFMA-LSTM with 16 blocks made weights resident
// (VGPR 76) but widened the h-exchange fan-in 4->16 producers per consumer;
// all-to-all tag-poll across XCDs = 5.6us/step of pure stall (VALUBusy 0.4%).
// Lesson: the recurrence is bound by exchange topology, not matvec math.
// R13: proven R9 skeleton (64 blocks, fan-in 4, 1 poller/word, 2 barriers)
// + amdgpu_waves_per_eu(4,4): pins occupancy at exactly 4 waves/EU (1 block/
// CU), so the allocator's budget is 128 VGPR and squeezing below it buys
// nothing -> wv[16] (64 VGPR) stays resident; weight stream eliminated.
// ---------------------------------------------------------------------------

typedef __attribute__((ext_vector_type(8))) __bf16 bf16x8;
typedef __attribute__((ext_vector_type(4))) float f32x4;

__device__ __forceinline__ float sigmoidf_(float x) { return 1.f / (1.f + expf(-x)); }

__device__ __forceinline__ float fsig_(float x) {
  return __builtin_amdgcn_rcpf(1.f + __expf(-x));
}
__device__ __forceinline__ float ftanh_(float x) {
  float xc = fminf(fmaxf(x, -15.f), 15.f);
  float e = __expf(2.f * xc);
  return (e - 1.f) * __builtin_amdgcn_rcpf(e + 1.f);
}

__device__ __forceinline__ unsigned short f2bf(float f) {   // RNE
  unsigned u = __float_as_uint(f);
  unsigned r = (u + 0x7fffu + ((u >> 16) & 1u)) >> 16;
  return (unsigned short)r;
}
__device__ __forceinline__ float bf2f(unsigned short h) {
  return __uint_as_float(((unsigned)h) << 16);
}

// ---------------- fold BN into conv weights (fp32 path + bias) ----------
struct FoldPack {
  const float *w[6], *g[6], *b[6], *m[6], *v[6];
  float *wf[6], *bias[6];
  int oc[6], ic[6];
};

__global__ __launch_bounds__(256) void fold_all(FoldPack p) {
  const int layer = blockIdx.y;
  const int OC = p.oc[layer], IC = p.ic[layer];
  const int total = OC * IC * 9;
  const float* w = p.w[layer];
  float* wf = p.wf[layer];
  for (int i = blockIdx.x * 256 + threadIdx.x; i < total; i += gridDim.x * 256) {
    int oc = i / (IC * 9);
    int r  = i % (IC * 9);
    int ic = r / 9;
    int k  = r % 9;
    int ky = k / 3, kx = k % 3;
    float inv = p.g[layer][oc] / sqrtf(p.v[layer][oc] + 1e-5f);
    wf[(((ic * 3 + ky) * OC) + oc) * 4 + kx] = w[i] * inv;
  }
  if (blockIdx.x == 0) {
    int i = threadIdx.x;
    if (i < OC) {
      float inv = p.g[layer][i] / sqrtf(p.v[layer][i] + 1e-5f);
      p.bias[layer][i] = p.b[layer][i] - p.m[layer][i] * inv;
    }
  }
}

// ---------------- pack BN-folded weights into MFMA A-frag layout ----------
// A[m=oc][k], k = tap*IC + ic (tap-major). Layout: [mt*KG+g][lane(64)][8]
// where lane -> (m = mt*16 + (lane&15), k = 32g + 8*(lane>>4) + j).
// k >= Kreal -> 0 (zero tap-9 padding for IC=16 layers). bf16 hi + lo.
struct PackPack {
  const float *w[5], *g[5], *v[5];
  unsigned short *wh[5], *wl[5];
  int ic[5], oc[5], kg[5], kreal[5];
};

__global__ __launch_bounds__(256) void pack_w(PackPack p) {
  const int layer = blockIdx.y;
  const int IC = p.ic[layer], KG = p.kg[layer], K = p.kreal[layer];
  const int MT = p.oc[layer] / 16;
  const int total = MT * KG * 512;
  for (int i = blockIdx.x * 256 + threadIdx.x; i < total; i += gridDim.x * 256) {
    int j = i & 7;
    int lane = (i >> 3) & 63;
    int gmt = i >> 9;               // = mt*KG + g
    int m = (gmt / KG) * 16 + (lane & 15);
    int k = 32 * (gmt % KG) + 8 * (lane >> 4) + j;
    float val = 0.f;
    if (k < K) {
      int tap = k / IC, ic = k % IC;
      int ky = tap / 3, kx = tap % 3;
      float inv = p.g[layer][m] / sqrtf(p.v[layer][m] + 1e-5f);
      val = p.w[layer][((m * IC + ic) * 3 + ky) * 3 + kx] * inv;
    }
    unsigned short h = f2bf(val);
    p.wh[layer][i] = h;
    p.wl[layer][i] = f2bf(val - bf2f(h));
  }
}

// ---------------- fp32 direct conv (L0 only: IC=3, K=27) ----------------
template<int IC, int OC, int IH, int IW, int STRIDE, int TPOS, int SPLITY,
         int ICS, int MINW>
__global__ __launch_bounds__(256, MINW) void conv_bn_relu(
    const float* __restrict__ in, const float* __restrict__ wf,
    const float* __restrict__ bias, float* __restrict__ out)
{
  constexpr int OH = IH / STRIDE, OW = IW / STRIDE;
  constexpr int OHB = OH / SPLITY;
  constexpr int RIH = (SPLITY == 1) ? (IH + 2) : ((OHB - 1) * STRIDE + 3);
  constexpr int PIW = IW + 4;
  constexpr int PLANE = RIH * PIW;
  constexpr int NPOS = OHB * OW;
  constexpr int WPOS = NPOS / TPOS;
  constexpr int SLOT = WPOS * ICS;
  constexpr int GROUPS = 256 / SLOT;
  constexpr int TOC = OC / GROUPS;
  constexpr int CH = IC / ICS;
  constexpr int SPAN = (TPOS - 1) * STRIDE + 3;
  constexpr int NW = (SPAN + 3) / 4;
  constexpr int XSLOTS = OW / TPOS;
  static_assert(SLOT % 64 == 0 && GROUPS * SLOT == 256 && GROUPS * TOC == OC, "tiling");

  __shared__ float s_in[IC * PLANE];

  const int tid = threadIdx.x;
  const int n     = (SPLITY == 1) ? blockIdx.x : blockIdx.x / SPLITY;
  const int split = (SPLITY == 1) ? 0 : blockIdx.x % SPLITY;
  const int ry0 = split * OHB;
  const int r0  = ry0 * STRIDE - 1;

  for (int i = tid; i < IC * PLANE / 4; i += 256)
    ((float4*)s_in)[i] = float4{0.f, 0.f, 0.f, 0.f};
  __syncthreads();

  constexpr int ROWF4 = IW / 4;
  constexpr int NSTG = IC * RIH * ROWF4;
  for (int i = tid; i < NSTG; i += 256) {
    int rw  = i % ROWF4;
    int t   = i / ROWF4;
    int row = t % RIH;
    int ic  = t / RIH;
    int giy = r0 + row;
    if (giy >= 0 && giy < IH) {
      float4 v = *(const float4*)(in + ((size_t)(n * IC + ic) * IH + giy) * IW + rw * 4);
      float* dst = &s_in[(ic * RIH + row) * PIW + 1 + rw * 4];
      dst[0] = v.x; dst[1] = v.y; dst[2] = v.z; dst[3] = v.w;
    }
  }
  __syncthreads();

  const int group  = tid / SLOT;
  const int sl     = tid % SLOT;
  const int icq    = sl / WPOS;
  const int worker = sl % WPOS;
  const int oy  = worker / XSLOTS;
  const int ox0 = (worker % XSLOTS) * TPOS;
  const int xb  = ox0 * STRIDE;

  const int oc0u = __builtin_amdgcn_readfirstlane(group * TOC);
  const float4* wg = (const float4*)wf + oc0u;

  float acc[TOC][TPOS];
  #pragma unroll
  for (int a = 0; a < TOC; ++a)
    #pragma unroll
    for (int p = 0; p < TPOS; ++p) acc[a][p] = 0.f;

  for (int icl = 0; icl < CH; ++icl) {
    const int ic = icq * CH + icl;
    const float* sI = &s_in[ic * PLANE];
    #pragma unroll
    for (int ky = 0; ky < 3; ++ky) {
      float row[NW * 4];
      {
        const float4* rp = (const float4*)&sI[(oy * STRIDE + ky) * PIW + xb];
        #pragma unroll
        for (int w = 0; w < NW; ++w) {
          float4 t4 = rp[w];
          row[4*w+0] = t4.x; row[4*w+1] = t4.y;
          row[4*w+2] = t4.z; row[4*w+3] = t4.w;
        }
      }
      const float4* wrow = wg + (ic * 3 + ky) * OC;
      #pragma unroll
      for (int oc = 0; oc < TOC; ++oc) {
        float4 w4 = wrow[oc];
        #pragma unroll
        for (int p = 0; p < TPOS; ++p)
          acc[oc][p] = fmaf(row[p * STRIDE + 0], w4.x,
                       fmaf(row[p * STRIDE + 1], w4.y,
                       fmaf(row[p * STRIDE + 2], w4.z, acc[oc][p])));
      }
    }
  }

  #pragma unroll
  for (int d = WPOS; d < SLOT; d <<= 1)
    #pragma unroll
    for (int oc = 0; oc < TOC; ++oc)
      #pragma unroll
      for (int p = 0; p < TPOS; ++p)
        acc[oc][p] += __shfl_xor(acc[oc][p], d);

  if (icq == 0) {
    float* outN = out + (size_t)n * (OC * OH * OW);
    #pragma unroll
    for (int oc = 0; oc < TOC; ++oc) {
      const float bb = bias[oc0u + oc];
      float* op = outN + ((size_t)(oc0u + oc) * OH + (ry0 + oy)) * OW + ox0;
      #pragma unroll
      for (int vq = 0; vq < TPOS / 4; ++vq) {
        float4 val;
        val.x = fmaxf(acc[oc][vq*4+0] + bb, 0.f);
        val.y = fmaxf(acc[oc][vq*4+1] + bb, 0.f);
        val.z = fmaxf(acc[oc][vq*4+2] + bb, 0.f);
        val.w = fmaxf(acc[oc][vq*4+3] + bb, 0.f);
        *(float4*)(op + vq * 4) = val;
      }
    }
  }
}

// ---------------- MFMA implicit-GEMM conv (L1..L5) ----------------
// M=OC (A=packed weights, global), N=positions (B=input, LDS NHWC bf16 h/l),
// K=IC*9 (padded to KG*32). C row=oc (quad*4+reg), col=pos (lane&15).
template<int IC, int OC, int IH, int IW, int STRIDE, int SPLITY, int KG, int ZROW>
__global__ __launch_bounds__(256, 2) void conv_mfma(
    const float* __restrict__ in, const unsigned short* __restrict__ Ah,
    const unsigned short* __restrict__ Al, const float* __restrict__ bias,
    float* __restrict__ out)
{
  constexpr int OH = IH / STRIDE, OW = IW / STRIDE;
  constexpr int OHB = OH / SPLITY;
  constexpr int N = OHB * OW;
  constexpr int NT = N / 16;
  constexpr int NTW = NT / 4;              // n-tiles per wave
  constexpr int MT = OC / 16;
  constexpr int ICP = IC + 8;              // bank-skew pad (2-way worst, stride1)
  constexpr int PW = IW + 3;
  constexpr int PH = (OHB - 1) * STRIDE + 3 + ZROW;
  constexpr int SZ = ((PH * PW * ICP + 7) / 8) * 8;
  static_assert(NT % 4 == 0, "nt");

  __shared__ unsigned short s_h[SZ];
  __shared__ unsigned short s_l[SZ];

  const int tid = threadIdx.x;
  const int n     = (SPLITY == 1) ? blockIdx.x : blockIdx.x / SPLITY;
  const int split = (SPLITY == 1) ? 0 : blockIdx.x % SPLITY;
  const int y0 = split * OHB;
  const int r0 = y0 * STRIDE - 1;

  // zero both planes (halo + K-pad rows must be finite-zero)
  for (int i = tid * 8; i < SZ; i += 2048) {
    *(int4*)&s_h[i] = int4{0, 0, 0, 0};
    *(int4*)&s_l[i] = int4{0, 0, 0, 0};
  }
  __syncthreads();

  // stage NCHW fp32 -> NHWC bf16 hi/lo (rows clipped at runtime)
  constexpr int ROWF4 = IW / 4;
  for (int i = tid; i < IC * PH * ROWF4; i += 256) {
    int rw  = i % ROWF4;
    int t   = i / ROWF4;
    int row = t % PH;
    int ic  = t / PH;
    int giy = r0 + row;
    if (giy >= 0 && giy < IH) {
      float4 v = *(const float4*)(in + ((size_t)(n * IC + ic) * IH + giy) * IW + rw * 4);
      int base = (row * PW + rw * 4 + 1) * ICP + ic;
      float vv[4] = {v.x, v.y, v.z, v.w};
      #pragma unroll
      for (int e = 0; e < 4; ++e) {
        unsigned short h = f2bf(vv[e]);
        s_h[base + e * ICP] = h;
        s_l[base + e * ICP] = f2bf(vv[e] - bf2f(h));
      }
    }
  }
  __syncthreads();

  const int wave = tid >> 6;
  const int lane = tid & 63;
  const int l16  = lane & 15;
  const int quad = lane >> 4;

  f32x4 acc[MT][NTW];
  #pragma unroll
  for (int mt = 0; mt < MT; ++mt)
    #pragma unroll
    for (int nt = 0; nt < NTW; ++nt) acc[mt][nt] = f32x4{0.f, 0.f, 0.f, 0.f};

  for (int g = 0; g < KG; ++g) {
    // per-lane k decomposition (IC pow2 -> shifts; tap<=9)
    const int k0 = 32 * g + 8 * quad;
    const int tap = k0 / IC;
    const int ic0 = k0 % IC;
    const int ky = tap / 3;
    const int kx = tap - ky * 3;
    bf16x8 afh[MT], afl[MT];
    #pragma unroll
    for (int mt = 0; mt < MT; ++mt) {
      size_t wo = ((size_t)(mt * KG + g) * 64 + lane) * 8;
      afh[mt] = __builtin_bit_cast(bf16x8, *(const int4*)(Ah + wo));
      afl[mt] = __builtin_bit_cast(bf16x8, *(const int4*)(Al + wo));
    }
    #pragma unroll
    for (int nt = 0; nt < NTW; ++nt) {
      int p = (wave * NTW + nt) * 16 + l16;
      int py = p / OW, px = p % OW;
      int addr = ((py * STRIDE + ky) * PW + px * STRIDE + kx) * ICP + ic0;
      bf16x8 bh = __builtin_bit_cast(bf16x8, *(const int4*)&s_h[addr]);
      bf16x8 bl = __builtin_bit_cast(bf16x8, *(const int4*)&s_l[addr]);
      #pragma unroll
      for (int mt = 0; mt < MT; ++mt) {
        acc[mt][nt] = __builtin_amdgcn_mfma_f32_16x16x32_bf16(afh[mt], bh, acc[mt][nt], 0, 0, 0);
        acc[mt][nt] = __builtin_amdgcn_mfma_f32_16x16x32_bf16(afh[mt], bl, acc[mt][nt], 0, 0, 0);
        acc[mt][nt] = __builtin_amdgcn_mfma_f32_16x16x32_bf16(afl[mt], bh, acc[mt][nt], 0, 0, 0);
      }
    }
  }

  // epilogue: bias + relu, NCHW store (col=pos coalesced per oc-row)
  #pragma unroll
  for (int mt = 0; mt < MT; ++mt)
    #pragma unroll
    for (int nt = 0; nt < NTW; ++nt) {
      int p = (wave * NTW + nt) * 16 + l16;
      int py = p / OW, px = p % OW;
      #pragma unroll
      for (int r = 0; r < 4; ++r) {
        int oc = mt * 16 + quad * 4 + r;
        float v = acc[mt][nt][r] + bias[oc];
        out[((size_t)(n * OC + oc) * OH + y0 + py) * OW + px] = fmaxf(v, 0.f);
      }
    }
}

// ---------------- bf16 hi/lo split prepass (GEMM inputs) ----------------
__global__ __launch_bounds__(256) void split_a(
    const float* __restrict__ feats, unsigned short* __restrict__ ah,
    unsigned short* __restrict__ al)
{
  int i4 = blockIdx.x * 256 + threadIdx.x;
  int e = i4 * 4;
  int n = e >> 12;
  int k = e & 4095;
  int r = (n & 63) * 16 + (n >> 6);
  float4 v = ((const float4*)feats)[i4];
  ushort4 h, l;
  h.x = f2bf(v.x); l.x = f2bf(v.x - bf2f(h.x));
  h.y = f2bf(v.y); l.y = f2bf(v.y - bf2f(h.y));
  h.z = f2bf(v.z); l.z = f2bf(v.z - bf2f(h.z));
  h.w = f2bf(v.w); l.w = f2bf(v.w - bf2f(h.w));
  *(ushort4*)(ah + (size_t)r * 4096 + k) = h;
  *(ushort4*)(al + (size_t)r * 4096 + k) = l;
}

__global__ __launch_bounds__(256) void split_b(
    const float* __restrict__ w_ih, unsigned short* __restrict__ bh,
    unsigned short* __restrict__ bl)
{
  int i4 = blockIdx.x * 256 + threadIdx.x;
  float4 v = ((const float4*)w_ih)[i4];
  ushort4 h, l;
  h.x = f2bf(v.x); l.x = f2bf(v.x - bf2f(h.x));
  h.y = f2bf(v.y); l.y = f2bf(v.y - bf2f(h.y));
  h.z = f2bf(v.z); l.z = f2bf(v.z - bf2f(h.z));
  h.w = f2bf(v.w); l.w = f2bf(v.w - bf2f(h.w));
  ((ushort4*)bh)[i4] = h;
  ((ushort4*)bl)[i4] = l;
}

// ---------------- Xg partials: bf16 split-MFMA GEMM ----------------
__global__ __launch_bounds__(256) void mfma_xg(
    const unsigned short* __restrict__ Ah, const unsigned short* __restrict__ Al,
    const unsigned short* __restrict__ Bh, const unsigned short* __restrict__ Bl,
    float* __restrict__ part)
{
  __shared__ unsigned short s_ah[128 * 40];
  __shared__ unsigned short s_al[128 * 40];
  __shared__ unsigned short s_bh[128 * 40];
  __shared__ unsigned short s_bl[128 * 40];

  const int tid = threadIdx.x;
  const int col0 = blockIdx.x * 128;
  const int row0 = blockIdx.y * 128;
  const int kbase = blockIdx.z * 512;
  float* outp = part + (size_t)blockIdx.z * 1048576;

  const int wave = tid >> 6;
  const int lane = tid & 63;
  const int wr = wave >> 1, wc = wave & 1;
  const int quad = lane >> 4;
  const int l16 = lane & 15;

  f32x4 acc[4][4];
  #pragma unroll
  for (int i = 0; i < 4; ++i)
    #pragma unroll
    for (int j = 0; j < 4; ++j) acc[i][j] = f32x4{0.f, 0.f, 0.f, 0.f};

  for (int step = 0; step < 16; ++step) {
    const int koff = kbase + step * 32;
    #pragma unroll
    for (int c = tid; c < 512; c += 256) {
      int row = c >> 2, kc = (c & 3) * 8;
      int4 va = *(const int4*)(Ah + (size_t)(row0 + row) * 4096 + koff + kc);
      int4 vb = *(const int4*)(Al + (size_t)(row0 + row) * 4096 + koff + kc);
      int4 vc = *(const int4*)(Bh + (size_t)(col0 + row) * 4096 + koff + kc);
      int4 vd = *(const int4*)(Bl + (size_t)(col0 + row) * 4096 + koff + kc);
      *(int4*)&s_ah[row * 40 + kc] = va;
      *(int4*)&s_al[row * 40 + kc] = vb;
      *(int4*)&s_bh[row * 40 + kc] = vc;
      *(int4*)&s_bl[row * 40 + kc] = vd;
    }
    __syncthreads();

    bf16x8 arh[4], arl[4];
    #pragma unroll
    for (int i = 0; i < 4; ++i) {
      int m = wr * 64 + i * 16 + l16;
      arh[i] = __builtin_bit_cast(bf16x8, *(const int4*)&s_ah[m * 40 + quad * 8]);
      arl[i] = __builtin_bit_cast(bf16x8, *(const int4*)&s_al[m * 40 + quad * 8]);
    }
    #pragma unroll
    for (int j = 0; j < 4; ++j) {
      int nn = wc * 64 + j * 16 + l16;
      bf16x8 brh = __builtin_bit_cast(bf16x8, *(const int4*)&s_bh[nn * 40 + quad * 8]);
      bf16x8 brl = __builtin_bit_cast(bf16x8, *(const int4*)&s_bl[nn * 40 + quad * 8]);
      #pragma unroll
      for (int i = 0; i < 4; ++i) {
        acc[i][j] = __builtin_amdgcn_mfma_f32_16x16x32_bf16(arh[i], brh, acc[i][j], 0, 0, 0);
        acc[i][j] = __builtin_amdgcn_mfma_f32_16x16x32_bf16(arh[i], brl, acc[i][j], 0, 0, 0);
        acc[i][j] = __builtin_amdgcn_mfma_f32_16x16x32_bf16(arl[i], brh, acc[i][j], 0, 0, 0);
      }
    }
    __syncthreads();
  }

  #pragma unroll
  for (int i = 0; i < 4; ++i)
    #pragma unroll
    for (int j = 0; j < 4; ++j) {
      int row = row0 + wr * 64 + i * 16 + quad * 4;
      int col = col0 + wc * 64 + j * 16 + l16;
      #pragma unroll
      for (int r = 0; r < 4; ++r)
        outp[(size_t)(row + r) * 1024 + col] = acc[i][j][r];
    }
}

// xg = sum_z p[z] + (b_ih + b_hh)
__global__ __launch_bounds__(256) void reduce_xg(
    const float* __restrict__ p, const float* __restrict__ b_ih,
    const float* __restrict__ b_hh, float* __restrict__ xg)
{
  int i = blockIdx.x * 256 + threadIdx.x;
  float4 s = {0.f, 0.f, 0.f, 0.f};
  #pragma unroll
  for (int z = 0; z < 8; ++z) {
    float4 a = ((const float4*)p)[(size_t)z * 262144 + i];
    s.x += a.x; s.y += a.y; s.z += a.z; s.w += a.w;
  }
  int cb = i & 255;
  float4 bi = ((const float4*)b_ih)[cb];
  float4 bh = ((const float4*)b_hh)[cb];
  float4 o;
  o.x = s.x + bi.x + bh.x;
  o.y = s.y + bi.y + bh.y;
  o.z = s.z + bi.z + bh.z;
  o.w = s.w + bi.w + bh.w;
  ((float4*)xg)[i] = o;
}

// ---------------- persistent LSTM recurrence ----------------
// R9 skeleton (proven 101-108us): 64 blocks = 16 b x 4 j-chunks; r=tid>>2
// (gate-row 0..255), q=tid&3 (K-quarter). tid<256 polls hpair (1 poller/word,
// fan-in 4 producer blocks -- the exchange topology R12 proved critical);
// LDS s_h broadcast; 16xfloat4 FMA matvec; q-reduce 2 shfl_xor; gate combine
// via s_gates LDS + barrier.
// R13: amdgpu_waves_per_eu(4,4) pins occupancy at exactly 4 waves/EU = 1
// block/CU. R10/R11 failed because launch_bounds' 2nd arg is only a MIN --
// the allocator still targeted 8 waves/EU (<=64 VGPR) and rematerialized/
// spilled wv, re-streaming w_hh 256KB/CU/step from L2 (~1.1us/step). With
// max pinned to 4, the budget is 128 VGPR and there is no occupancy reward
// for squeezing -> wv[16] (64 VGPR) stays resident. asm pin kept (blocks
// remat). Fast __expf/v_rcp gates (bit-identical absmax, R10/R11).
__global__ __launch_bounds__(1024)
__attribute__((amdgpu_waves_per_eu(4, 4)))
void lstm_kernel(
    const float* __restrict__ xg, const float* __restrict__ w_hh,
    float* __restrict__ hs, unsigned long long* __restrict__ hpair)
{
  const int b = blockIdx.x & 15;
  const int g = blockIdx.x >> 4;
  const int tid = threadIdx.x;
  const int r = tid >> 2;
  const int q = tid & 3;
  const int gate = r >> 6;
  const int jl = r & 63;
  const int j = g * 64 + jl;

  float4 wv[16];
  {
    const float4* wrow = (const float4*)(w_hh + ((size_t)(gate * 256 + j)) * 256 + q * 64);
    #pragma unroll
    for (int k = 0; k < 16; ++k) wv[k] = wrow[k];
  }
  // Pin: opaque asm defs can't be rematerialized -> weights stay in VGPRs.
  #pragma unroll
  for (int k = 0; k < 16; ++k)
    asm volatile("" : "+v"(wv[k].x), "+v"(wv[k].y), "+v"(wv[k].z), "+v"(wv[k].w));

  __shared__ float s_h[4 * 72];
  __shared__ float s_gates[4][64];
  float c_reg = 0.f;

  for (int s = 0; s < 64; ++s) {
    float xv = 0.f;
    if (q == 0) xv = xg[(size_t)(s * 16 + b) * 1024 + gate * 256 + j];
    float gv = 0.f;
    if (s > 0) {
      if (tid < 256) {
        const unsigned long long* src = hpair + ((size_t)(s - 1) * 16 + b) * 256 + tid;
        unsigned long long pv;
        do {
          pv = __hip_atomic_load(src, __ATOMIC_RELAXED, __HIP_MEMORY_SCOPE_AGENT);
        } while ((unsigned int)(pv >> 32) != (unsigned int)s);
        s_h[(tid >> 6) * 72 + (tid & 63)] = __uint_as_float((unsigned int)pv);
      }
      __syncthreads();
      const float4* hp = (const float4*)&s_h[q * 72];
      float p = 0.f;
      #pragma unroll
      for (int k = 0; k < 16; ++k) {
        float4 h4 = hp[k];
        p = fmaf(h4.x, wv[k].x, p);
        p = fmaf(h4.y, wv[k].y, p);
        p = fmaf(h4.z, wv[k].z, p);
        p = fmaf(h4.w, wv[k].w, p);
      }
      p += __shfl_xor(p, 1);
      p += __shfl_xor(p, 2);
      gv = p;
    }
    if (q == 0) s_gates[gate][jl] = gv + xv;
    __syncthreads();
    if (tid < 64) {
      float gi = s_gates[0][tid], gf = s_gates[1][tid];
      float gg = s_gates[2][tid], go = s_gates[3][tid];
      float cn = fsig_(gf) * c_reg + fsig_(gi) * ftanh_(gg);
      c_reg = cn;
      float hv = fsig_(go) * ftanh_(cn);
      hs[(size_t)s * 4096 + b * 256 + g * 64 + tid] = hv;
      unsigned long long pv =
          ((unsigned long long)(unsigned int)(s + 1) << 32) | __float_as_uint(hv);
      __hip_atomic_store(hpair + ((size_t)s * 16 + b) * 256 + g * 64 + tid, pv,
                         __ATOMIC_RELAXED, __HIP_MEMORY_SCOPE_AGENT);
    }
  }
}

// ---------------- classifier head ----------------
__global__ __launch_bounds__(64) void cls_kernel(
    const float* __restrict__ hs, const float* __restrict__ cw,
    const float* __restrict__ cb, float* __restrict__ out)
{
  const int id = blockIdx.x;
  const int b = id / 53;
  const int t = id % 53;
  const int s = 11 + t;
  const int lane = threadIdx.x;
  float4 hv = ((const float4*)(hs + (size_t)s * 4096 + b * 256))[lane];
  float4 wv = ((const float4*)cw)[lane];
  float p = hv.x * wv.x + hv.y * wv.y + hv.z * wv.z + hv.w * wv.w;
  #pragma unroll
  for (int off = 32; off >= 1; off >>= 1) p += __shfl_xor(p, off);
  if (lane == 0) out[id] = tanhf(p + cb[0]);
}

// ---------------------------------------------------------------------------
extern "C" void kernel_launch(void* const* d_in, const int* in_sizes, int n_in,
                              void* d_out, int out_size, void* d_ws, size_t ws_size,
                              hipStream_t stream)
{
  (void)in_sizes; (void)n_in; (void)out_size; (void)ws_size;
  const float* imgs = (const float*)d_in[0];
  const float* w_ih  = (const float*)d_in[31];
  const float* w_hh  = (const float*)d_in[32];
  const float* b_ih  = (const float*)d_in[33];
  const float* b_hh  = (const float*)d_in[34];
  const float* cls_w = (const float*)d_in[35];
  const float* cls_b = (const float*)d_in[36];
  float* out = (float*)d_out;

  float* ws   = (float*)d_ws;
  float* actA = ws;
  float* actB = actA + 16777216;
  float* xg   = actB + 16777216;
  float* hs   = xg + 1048576;
  unsigned long long* hpair = (unsigned long long*)(hs + 262144);
  float* wfp  = hs + 262144 + 524288;
  static const int ocs[6] = {16, 16, 32, 32, 64, 64};
  static const int ics[6] = {3, 16, 16, 32, 32, 64};
  float* wf[6];
  size_t off = 0;
  for (int i = 0; i < 6; ++i) { wf[i] = wfp + off; off += (size_t)ocs[i] * ics[i] * 12; }
  float* biasp = wfp + off;
  float* bias[6];
  for (int i = 0; i < 6; ++i) bias[i] = biasp + i * 64;

  // packed MFMA weights (L1..L5): sizes MT*KG*512 ushorts per plane
  static const int psz[5] = {2560, 5120, 9216, 18432, 36864};
  unsigned short* WH = (unsigned short*)(biasp + 6 * 64);
  unsigned short* WL = WH + 72192;
  unsigned short *wh[5], *wl[5];
  {
    int o = 0;
    for (int i = 0; i < 5; ++i) { wh[i] = WH + o; wl[i] = WL + o; o += psz[i]; }
  }

  float* partials = actA;       // reused post-conv
  unsigned short* Ah = (unsigned short*)(actA + 8388608);
  unsigned short* Al = Ah + 4194304;
  unsigned short* Bh = Al + 4194304;
  unsigned short* Bl = Bh + 4194304;

  FoldPack fp;
  for (int i = 0; i < 6; ++i) {
    fp.w[i] = (const float*)d_in[1 + 5*i];
    fp.g[i] = (const float*)d_in[2 + 5*i];
    fp.b[i] = (const float*)d_in[3 + 5*i];
    fp.m[i] = (const float*)d_in[4 + 5*i];
    fp.v[i] = (const float*)d_in[5 + 5*i];
    fp.wf[i] = wf[i];
    fp.bias[i] = bias[i];
    fp.oc[i] = ocs[i];
    fp.ic[i] = ics[i];
  }
  fold_all<<<dim3(8, 6), 256, 0, stream>>>(fp);

  PackPack pp;
  static const int kgs[5] = {5, 5, 9, 9, 18};
  static const int krs[5] = {144, 144, 288, 288, 576};
  for (int i = 0; i < 5; ++i) {
    pp.w[i] = (const float*)d_in[1 + 5*(i+1)];
    pp.g[i] = (const float*)d_in[2 + 5*(i+1)];
    pp.v[i] = (const float*)d_in[5 + 5*(i+1)];
    pp.wh[i] = wh[i];
    pp.wl[i] = wl[i];
    pp.ic[i] = ics[i+1];
    pp.oc[i] = ocs[i+1];
    pp.kg[i] = kgs[i];
    pp.kreal[i] = krs[i];
  }
  pack_w<<<dim3(36, 5), 256, 0, stream>>>(pp);

  // L0 fp32 direct conv
  conv_bn_relu<3, 16, 64, 64, 2, 4, 2, 1, 4><<<2048, 256, 0, stream>>>(imgs, wf[0], bias[0], actA);
  //            IC  OC  IH  IW  S SPL KG ZR
  conv_mfma<16, 16, 32, 32, 1, 4, 5, 1><<<4096, 256, 0, stream>>>(actA, wh[0], wl[0], bias[1], actB);
  conv_mfma<16, 32, 32, 32, 2, 4, 5, 1><<<4096, 256, 0, stream>>>(actB, wh[1], wl[1], bias[2], actA);
  conv_mfma<32, 32, 16, 16, 1, 1, 9, 0><<<1024, 256, 0, stream>>>(actA, wh[2], wl[2], bias[3], actB);
  conv_mfma<32, 64, 16, 16, 2, 1, 9, 0><<<1024, 256, 0, stream>>>(actB, wh[3], wl[3], bias[4], actA);
  conv_mfma<64, 64,  8,  8, 1, 1, 18, 0><<<1024, 256, 0, stream>>>(actA, wh[4], wl[4], bias[5], actB);

  split_a<<<4096, 256, 0, stream>>>(actB, Ah, Al);
  split_b<<<4096, 256, 0, stream>>>(w_ih, Bh, Bl);
  mfma_xg<<<dim3(8, 8, 8), 256, 0, stream>>>(Ah, Al, Bh, Bl, partials);
  reduce_xg<<<1024, 256, 0, stream>>>(partials, b_ih, b_hh, xg);
  lstm_kernel<<<64, 1024, 0, stream>>>(xg, w_hh, hs, hpair);
  cls_kernel<<<848, 64, 0, stream>>>(hs, cls_w, cls_b, out);
}

// Round 5
// 479.286 us; speedup vs baseline: 1.5470x; 1.0186x over previous
//
#include <hip/hip_runtime.h>
#include <cmath>

// ---------------------------------------------------------------------------
// 6x (conv3x3+BN+ReLU) -> LSTM(4096->256) over S=64 -> tanh(linear).
// R9: convs L1..L5 ported to split-bf16 MFMA implicit-GEMM (hh+hl+lh, proven
// absmax 3e-8). L0 (K=27) stays fp32.
// R10/R11/R13 (FAILED): three attempts to hold a 64-VGPR weight array in a
// 1024-thread block (launch_bounds min-waves, asm pin, waves_per_eu(4,4))
// all lost to the allocator: 64 pinned + ~25 working > its 64-VGPR/8-wave
// budget -> remat/spill, w_hh re-streamed 256KB/CU/step from L2 (~1.1us of
// the 1.6us step). HARD RULE: 64-VGPR arrays don't survive 16-wave blocks.
// R12 (FAILED, 356us): MFMA-LSTM coupled all 16 batches through one poll
// (global straggler every step, 5.6us/step). RULE: keep batches decoupled.
// R14: structural fix -- shrink per-thread weights to 32 VGPR so the whole
// working set (~57) fits UNDER the 64-VGPR budget; the allocator then has
// zero incentive to evict (no occupancy step below 64). 128 blocks = 16 b
// x 8 j-chunks of 32; tid=r*8+q (r=128 gate-rows, q=K-eighth of 32 floats,
// q in lane-low-bits -> K-reduce is 3 shfl_xor). h windows in s_h2[8][36]
// (+4 pad: 8 per-q broadcast addrs -> 8 distinct bank-quads, conflict-free).
// Fan-in 8, batch-decoupled; 2 barriers/step; fast __expf/v_rcp gates.
// ---------------------------------------------------------------------------

typedef __attribute__((ext_vector_type(8))) __bf16 bf16x8;
typedef __attribute__((ext_vector_type(4))) float f32x4;

__device__ __forceinline__ float sigmoidf_(float x) { return 1.f / (1.f + expf(-x)); }

__device__ __forceinline__ float fsig_(float x) {
  return __builtin_amdgcn_rcpf(1.f + __expf(-x));
}
__device__ __forceinline__ float ftanh_(float x) {
  float xc = fminf(fmaxf(x, -15.f), 15.f);
  float e = __expf(2.f * xc);
  return (e - 1.f) * __builtin_amdgcn_rcpf(e + 1.f);
}

__device__ __forceinline__ unsigned short f2bf(float f) {   // RNE
  unsigned u = __float_as_uint(f);
  unsigned r = (u + 0x7fffu + ((u >> 16) & 1u)) >> 16;
  return (unsigned short)r;
}
__device__ __forceinline__ float bf2f(unsigned short h) {
  return __uint_as_float(((unsigned)h) << 16);
}

// ---------------- fold BN into conv weights (fp32 path + bias) ----------
struct FoldPack {
  const float *w[6], *g[6], *b[6], *m[6], *v[6];
  float *wf[6], *bias[6];
  int oc[6], ic[6];
};

__global__ __launch_bounds__(256) void fold_all(FoldPack p) {
  const int layer = blockIdx.y;
  const int OC = p.oc[layer], IC = p.ic[layer];
  const int total = OC * IC * 9;
  const float* w = p.w[layer];
  float* wf = p.wf[layer];
  for (int i = blockIdx.x * 256 + threadIdx.x; i < total; i += gridDim.x * 256) {
    int oc = i / (IC * 9);
    int r  = i % (IC * 9);
    int ic = r / 9;
    int k  = r % 9;
    int ky = k / 3, kx = k % 3;
    float inv = p.g[layer][oc] / sqrtf(p.v[layer][oc] + 1e-5f);
    wf[(((ic * 3 + ky) * OC) + oc) * 4 + kx] = w[i] * inv;
  }
  if (blockIdx.x == 0) {
    int i = threadIdx.x;
    if (i < OC) {
      float inv = p.g[layer][i] / sqrtf(p.v[layer][i] + 1e-5f);
      p.bias[layer][i] = p.b[layer][i] - p.m[layer][i] * inv;
    }
  }
}

// ---------------- pack BN-folded weights into MFMA A-frag layout ----------
// A[m=oc][k], k = tap*IC + ic (tap-major). Layout: [mt*KG+g][lane(64)][8]
// where lane -> (m = mt*16 + (lane&15), k = 32g + 8*(lane>>4) + j).
// k >= Kreal -> 0 (zero tap-9 padding for IC=16 layers). bf16 hi + lo.
struct PackPack {
  const float *w[5], *g[5], *v[5];
  unsigned short *wh[5], *wl[5];
  int ic[5], oc[5], kg[5], kreal[5];
};

__global__ __launch_bounds__(256) void pack_w(PackPack p) {
  const int layer = blockIdx.y;
  const int IC = p.ic[layer], KG = p.kg[layer], K = p.kreal[layer];
  const int MT = p.oc[layer] / 16;
  const int total = MT * KG * 512;
  for (int i = blockIdx.x * 256 + threadIdx.x; i < total; i += gridDim.x * 256) {
    int j = i & 7;
    int lane = (i >> 3) & 63;
    int gmt = i >> 9;               // = mt*KG + g
    int m = (gmt / KG) * 16 + (lane & 15);
    int k = 32 * (gmt % KG) + 8 * (lane >> 4) + j;
    float val = 0.f;
    if (k < K) {
      int tap = k / IC, ic = k % IC;
      int ky = tap / 3, kx = tap % 3;
      float inv = p.g[layer][m] / sqrtf(p.v[layer][m] + 1e-5f);
      val = p.w[layer][((m * IC + ic) * 3 + ky) * 3 + kx] * inv;
    }
    unsigned short h = f2bf(val);
    p.wh[layer][i] = h;
    p.wl[layer][i] = f2bf(val - bf2f(h));
  }
}

// ---------------- fp32 direct conv (L0 only: IC=3, K=27) ----------------
template<int IC, int OC, int IH, int IW, int STRIDE, int TPOS, int SPLITY,
         int ICS, int MINW>
__global__ __launch_bounds__(256, MINW) void conv_bn_relu(
    const float* __restrict__ in, const float* __restrict__ wf,
    const float* __restrict__ bias, float* __restrict__ out)
{
  constexpr int OH = IH / STRIDE, OW = IW / STRIDE;
  constexpr int OHB = OH / SPLITY;
  constexpr int RIH = (SPLITY == 1) ? (IH + 2) : ((OHB - 1) * STRIDE + 3);
  constexpr int PIW = IW + 4;
  constexpr int PLANE = RIH * PIW;
  constexpr int NPOS = OHB * OW;
  constexpr int WPOS = NPOS / TPOS;
  constexpr int SLOT = WPOS * ICS;
  constexpr int GROUPS = 256 / SLOT;
  constexpr int TOC = OC / GROUPS;
  constexpr int CH = IC / ICS;
  constexpr int SPAN = (TPOS - 1) * STRIDE + 3;
  constexpr int NW = (SPAN + 3) / 4;
  constexpr int XSLOTS = OW / TPOS;
  static_assert(SLOT % 64 == 0 && GROUPS * SLOT == 256 && GROUPS * TOC == OC, "tiling");

  __shared__ float s_in[IC * PLANE];

  const int tid = threadIdx.x;
  const int n     = (SPLITY == 1) ? blockIdx.x : blockIdx.x / SPLITY;
  const int split = (SPLITY == 1) ? 0 : blockIdx.x % SPLITY;
  const int ry0 = split * OHB;
  const int r0  = ry0 * STRIDE - 1;

  for (int i = tid; i < IC * PLANE / 4; i += 256)
    ((float4*)s_in)[i] = float4{0.f, 0.f, 0.f, 0.f};
  __syncthreads();

  constexpr int ROWF4 = IW / 4;
  constexpr int NSTG = IC * RIH * ROWF4;
  for (int i = tid; i < NSTG; i += 256) {
    int rw  = i % ROWF4;
    int t   = i / ROWF4;
    int row = t % RIH;
    int ic  = t / RIH;
    int giy = r0 + row;
    if (giy >= 0 && giy < IH) {
      float4 v = *(const float4*)(in + ((size_t)(n * IC + ic) * IH + giy) * IW + rw * 4);
      float* dst = &s_in[(ic * RIH + row) * PIW + 1 + rw * 4];
      dst[0] = v.x; dst[1] = v.y; dst[2] = v.z; dst[3] = v.w;
    }
  }
  __syncthreads();

  const int group  = tid / SLOT;
  const int sl     = tid % SLOT;
  const int icq    = sl / WPOS;
  const int worker = sl % WPOS;
  const int oy  = worker / XSLOTS;
  const int ox0 = (worker % XSLOTS) * TPOS;
  const int xb  = ox0 * STRIDE;

  const int oc0u = __builtin_amdgcn_readfirstlane(group * TOC);
  const float4* wg = (const float4*)wf + oc0u;

  float acc[TOC][TPOS];
  #pragma unroll
  for (int a = 0; a < TOC; ++a)
    #pragma unroll
    for (int p = 0; p < TPOS; ++p) acc[a][p] = 0.f;

  for (int icl = 0; icl < CH; ++icl) {
    const int ic = icq * CH + icl;
    const float* sI = &s_in[ic * PLANE];
    #pragma unroll
    for (int ky = 0; ky < 3; ++ky) {
      float row[NW * 4];
      {
        const float4* rp = (const float4*)&sI[(oy * STRIDE + ky) * PIW + xb];
        #pragma unroll
        for (int w = 0; w < NW; ++w) {
          float4 t4 = rp[w];
          row[4*w+0] = t4.x; row[4*w+1] = t4.y;
          row[4*w+2] = t4.z; row[4*w+3] = t4.w;
        }
      }
      const float4* wrow = wg + (ic * 3 + ky) * OC;
      #pragma unroll
      for (int oc = 0; oc < TOC; ++oc) {
        float4 w4 = wrow[oc];
        #pragma unroll
        for (int p = 0; p < TPOS; ++p)
          acc[oc][p] = fmaf(row[p * STRIDE + 0], w4.x,
                       fmaf(row[p * STRIDE + 1], w4.y,
                       fmaf(row[p * STRIDE + 2], w4.z, acc[oc][p])));
      }
    }
  }

  #pragma unroll
  for (int d = WPOS; d < SLOT; d <<= 1)
    #pragma unroll
    for (int oc = 0; oc < TOC; ++oc)
      #pragma unroll
      for (int p = 0; p < TPOS; ++p)
        acc[oc][p] += __shfl_xor(acc[oc][p], d);

  if (icq == 0) {
    float* outN = out + (size_t)n * (OC * OH * OW);
    #pragma unroll
    for (int oc = 0; oc < TOC; ++oc) {
      const float bb = bias[oc0u + oc];
      float* op = outN + ((size_t)(oc0u + oc) * OH + (ry0 + oy)) * OW + ox0;
      #pragma unroll
      for (int vq = 0; vq < TPOS / 4; ++vq) {
        float4 val;
        val.x = fmaxf(acc[oc][vq*4+0] + bb, 0.f);
        val.y = fmaxf(acc[oc][vq*4+1] + bb, 0.f);
        val.z = fmaxf(acc[oc][vq*4+2] + bb, 0.f);
        val.w = fmaxf(acc[oc][vq*4+3] + bb, 0.f);
        *(float4*)(op + vq * 4) = val;
      }
    }
  }
}

// ---------------- MFMA implicit-GEMM conv (L1..L5) ----------------
// M=OC (A=packed weights, global), N=positions (B=input, LDS NHWC bf16 h/l),
// K=IC*9 (padded to KG*32). C row=oc (quad*4+reg), col=pos (lane&15).
template<int IC, int OC, int IH, int IW, int STRIDE, int SPLITY, int KG, int ZROW>
__global__ __launch_bounds__(256, 2) void conv_mfma(
    const float* __restrict__ in, const unsigned short* __restrict__ Ah,
    const unsigned short* __restrict__ Al, const float* __restrict__ bias,
    float* __restrict__ out)
{
  constexpr int OH = IH / STRIDE, OW = IW / STRIDE;
  constexpr int OHB = OH / SPLITY;
  constexpr int N = OHB * OW;
  constexpr int NT = N / 16;
  constexpr int NTW = NT / 4;              // n-tiles per wave
  constexpr int MT = OC / 16;
  constexpr int ICP = IC + 8;              // bank-skew pad (2-way worst, stride1)
  constexpr int PW = IW + 3;
  constexpr int PH = (OHB - 1) * STRIDE + 3 + ZROW;
  constexpr int SZ = ((PH * PW * ICP + 7) / 8) * 8;
  static_assert(NT % 4 == 0, "nt");

  __shared__ unsigned short s_h[SZ];
  __shared__ unsigned short s_l[SZ];

  const int tid = threadIdx.x;
  const int n     = (SPLITY == 1) ? blockIdx.x : blockIdx.x / SPLITY;
  const int split = (SPLITY == 1) ? 0 : blockIdx.x % SPLITY;
  const int y0 = split * OHB;
  const int r0 = y0 * STRIDE - 1;

  // zero both planes (halo + K-pad rows must be finite-zero)
  for (int i = tid * 8; i < SZ; i += 2048) {
    *(int4*)&s_h[i] = int4{0, 0, 0, 0};
    *(int4*)&s_l[i] = int4{0, 0, 0, 0};
  }
  __syncthreads();

  // stage NCHW fp32 -> NHWC bf16 hi/lo (rows clipped at runtime)
  constexpr int ROWF4 = IW / 4;
  for (int i = tid; i < IC * PH * ROWF4; i += 256) {
    int rw  = i % ROWF4;
    int t   = i / ROWF4;
    int row = t % PH;
    int ic  = t / PH;
    int giy = r0 + row;
    if (giy >= 0 && giy < IH) {
      float4 v = *(const float4*)(in + ((size_t)(n * IC + ic) * IH + giy) * IW + rw * 4);
      int base = (row * PW + rw * 4 + 1) * ICP + ic;
      float vv[4] = {v.x, v.y, v.z, v.w};
      #pragma unroll
      for (int e = 0; e < 4; ++e) {
        unsigned short h = f2bf(vv[e]);
        s_h[base + e * ICP] = h;
        s_l[base + e * ICP] = f2bf(vv[e] - bf2f(h));
      }
    }
  }
  __syncthreads();

  const int wave = tid >> 6;
  const int lane = tid & 63;
  const int l16  = lane & 15;
  const int quad = lane >> 4;

  f32x4 acc[MT][NTW];
  #pragma unroll
  for (int mt = 0; mt < MT; ++mt)
    #pragma unroll
    for (int nt = 0; nt < NTW; ++nt) acc[mt][nt] = f32x4{0.f, 0.f, 0.f, 0.f};

  for (int g = 0; g < KG; ++g) {
    // per-lane k decomposition (IC pow2 -> shifts; tap<=9)
    const int k0 = 32 * g + 8 * quad;
    const int tap = k0 / IC;
    const int ic0 = k0 % IC;
    const int ky = tap / 3;
    const int kx = tap - ky * 3;
    bf16x8 afh[MT], afl[MT];
    #pragma unroll
    for (int mt = 0; mt < MT; ++mt) {
      size_t wo = ((size_t)(mt * KG + g) * 64 + lane) * 8;
      afh[mt] = __builtin_bit_cast(bf16x8, *(const int4*)(Ah + wo));
      afl[mt] = __builtin_bit_cast(bf16x8, *(const int4*)(Al + wo));
    }
    #pragma unroll
    for (int nt = 0; nt < NTW; ++nt) {
      int p = (wave * NTW + nt) * 16 + l16;
      int py = p / OW, px = p % OW;
      int addr = ((py * STRIDE + ky) * PW + px * STRIDE + kx) * ICP + ic0;
      bf16x8 bh = __builtin_bit_cast(bf16x8, *(const int4*)&s_h[addr]);
      bf16x8 bl = __builtin_bit_cast(bf16x8, *(const int4*)&s_l[addr]);
      #pragma unroll
      for (int mt = 0; mt < MT; ++mt) {
        acc[mt][nt] = __builtin_amdgcn_mfma_f32_16x16x32_bf16(afh[mt], bh, acc[mt][nt], 0, 0, 0);
        acc[mt][nt] = __builtin_amdgcn_mfma_f32_16x16x32_bf16(afh[mt], bl, acc[mt][nt], 0, 0, 0);
        acc[mt][nt] = __builtin_amdgcn_mfma_f32_16x16x32_bf16(afl[mt], bh, acc[mt][nt], 0, 0, 0);
      }
    }
  }

  // epilogue: bias + relu, NCHW store (col=pos coalesced per oc-row)
  #pragma unroll
  for (int mt = 0; mt < MT; ++mt)
    #pragma unroll
    for (int nt = 0; nt < NTW; ++nt) {
      int p = (wave * NTW + nt) * 16 + l16;
      int py = p / OW, px = p % OW;
      #pragma unroll
      for (int r = 0; r < 4; ++r) {
        int oc = mt * 16 + quad * 4 + r;
        float v = acc[mt][nt][r] + bias[oc];
        out[((size_t)(n * OC + oc) * OH + y0 + py) * OW + px] = fmaxf(v, 0.f);
      }
    }
}

// ---------------- bf16 hi/lo split prepass (GEMM inputs) ----------------
__global__ __launch_bounds__(256) void split_a(
    const float* __restrict__ feats, unsigned short* __restrict__ ah,
    unsigned short* __restrict__ al)
{
  int i4 = blockIdx.x * 256 + threadIdx.x;
  int e = i4 * 4;
  int n = e >> 12;
  int k = e & 4095;
  int r = (n & 63) * 16 + (n >> 6);
  float4 v = ((const float4*)feats)[i4];
  ushort4 h, l;
  h.x = f2bf(v.x); l.x = f2bf(v.x - bf2f(h.x));
  h.y = f2bf(v.y); l.y = f2bf(v.y - bf2f(h.y));
  h.z = f2bf(v.z); l.z = f2bf(v.z - bf2f(h.z));
  h.w = f2bf(v.w); l.w = f2bf(v.w - bf2f(h.w));
  *(ushort4*)(ah + (size_t)r * 4096 + k) = h;
  *(ushort4*)(al + (size_t)r * 4096 + k) = l;
}

__global__ __launch_bounds__(256) void split_b(
    const float* __restrict__ w_ih, unsigned short* __restrict__ bh,
    unsigned short* __restrict__ bl)
{
  int i4 = blockIdx.x * 256 + threadIdx.x;
  float4 v = ((const float4*)w_ih)[i4];
  ushort4 h, l;
  h.x = f2bf(v.x); l.x = f2bf(v.x - bf2f(h.x));
  h.y = f2bf(v.y); l.y = f2bf(v.y - bf2f(h.y));
  h.z = f2bf(v.z); l.z = f2bf(v.z - bf2f(h.z));
  h.w = f2bf(v.w); l.w = f2bf(v.w - bf2f(h.w));
  ((ushort4*)bh)[i4] = h;
  ((ushort4*)bl)[i4] = l;
}

// ---------------- Xg partials: bf16 split-MFMA GEMM ----------------
__global__ __launch_bounds__(256) void mfma_xg(
    const unsigned short* __restrict__ Ah, const unsigned short* __restrict__ Al,
    const unsigned short* __restrict__ Bh, const unsigned short* __restrict__ Bl,
    float* __restrict__ part)
{
  __shared__ unsigned short s_ah[128 * 40];
  __shared__ unsigned short s_al[128 * 40];
  __shared__ unsigned short s_bh[128 * 40];
  __shared__ unsigned short s_bl[128 * 40];

  const int tid = threadIdx.x;
  const int col0 = blockIdx.x * 128;
  const int row0 = blockIdx.y * 128;
  const int kbase = blockIdx.z * 512;
  float* outp = part + (size_t)blockIdx.z * 1048576;

  const int wave = tid >> 6;
  const int lane = tid & 63;
  const int wr = wave >> 1, wc = wave & 1;
  const int quad = lane >> 4;
  const int l16 = lane & 15;

  f32x4 acc[4][4];
  #pragma unroll
  for (int i = 0; i < 4; ++i)
    #pragma unroll
    for (int j = 0; j < 4; ++j) acc[i][j] = f32x4{0.f, 0.f, 0.f, 0.f};

  for (int step = 0; step < 16; ++step) {
    const int koff = kbase + step * 32;
    #pragma unroll
    for (int c = tid; c < 512; c += 256) {
      int row = c >> 2, kc = (c & 3) * 8;
      int4 va = *(const int4*)(Ah + (size_t)(row0 + row) * 4096 + koff + kc);
      int4 vb = *(const int4*)(Al + (size_t)(row0 + row) * 4096 + koff + kc);
      int4 vc = *(const int4*)(Bh + (size_t)(col0 + row) * 4096 + koff + kc);
      int4 vd = *(const int4*)(Bl + (size_t)(col0 + row) * 4096 + koff + kc);
      *(int4*)&s_ah[row * 40 + kc] = va;
      *(int4*)&s_al[row * 40 + kc] = vb;
      *(int4*)&s_bh[row * 40 + kc] = vc;
      *(int4*)&s_bl[row * 40 + kc] = vd;
    }
    __syncthreads();

    bf16x8 arh[4], arl[4];
    #pragma unroll
    for (int i = 0; i < 4; ++i) {
      int m = wr * 64 + i * 16 + l16;
      arh[i] = __builtin_bit_cast(bf16x8, *(const int4*)&s_ah[m * 40 + quad * 8]);
      arl[i] = __builtin_bit_cast(bf16x8, *(const int4*)&s_al[m * 40 + quad * 8]);
    }
    #pragma unroll
    for (int j = 0; j < 4; ++j) {
      int nn = wc * 64 + j * 16 + l16;
      bf16x8 brh = __builtin_bit_cast(bf16x8, *(const int4*)&s_bh[nn * 40 + quad * 8]);
      bf16x8 brl = __builtin_bit_cast(bf16x8, *(const int4*)&s_bl[nn * 40 + quad * 8]);
      #pragma unroll
      for (int i = 0; i < 4; ++i) {
        acc[i][j] = __builtin_amdgcn_mfma_f32_16x16x32_bf16(arh[i], brh, acc[i][j], 0, 0, 0);
        acc[i][j] = __builtin_amdgcn_mfma_f32_16x16x32_bf16(arh[i], brl, acc[i][j], 0, 0, 0);
        acc[i][j] = __builtin_amdgcn_mfma_f32_16x16x32_bf16(arl[i], brh, acc[i][j], 0, 0, 0);
      }
    }
    __syncthreads();
  }

  #pragma unroll
  for (int i = 0; i < 4; ++i)
    #pragma unroll
    for (int j = 0; j < 4; ++j) {
      int row = row0 + wr * 64 + i * 16 + quad * 4;
      int col = col0 + wc * 64 + j * 16 + l16;
      #pragma unroll
      for (int r = 0; r < 4; ++r)
        outp[(size_t)(row + r) * 1024 + col] = acc[i][j][r];
    }
}

// xg = sum_z p[z] + (b_ih + b_hh)
__global__ __launch_bounds__(256) void reduce_xg(
    const float* __restrict__ p, const float* __restrict__ b_ih,
    const float* __restrict__ b_hh, float* __restrict__ xg)
{
  int i = blockIdx.x * 256 + threadIdx.x;
  float4 s = {0.f, 0.f, 0.f, 0.f};
  #pragma unroll
  for (int z = 0; z < 8; ++z) {
    float4 a = ((const float4*)p)[(size_t)z * 262144 + i];
    s.x += a.x; s.y += a.y; s.z += a.z; s.w += a.w;
  }
  int cb = i & 255;
  float4 bi = ((const float4*)b_ih)[cb];
  float4 bh = ((const float4*)b_hh)[cb];
  float4 o;
  o.x = s.x + bi.x + bh.x;
  o.y = s.y + bi.y + bh.y;
  o.z = s.z + bi.z + bh.z;
  o.w = s.w + bi.w + bh.w;
  ((float4*)xg)[i] = o;
}

// ---------------- persistent LSTM recurrence ----------------
// R14: 128 blocks = 16 batches x 8 j-chunks of 32 (batch-decoupled fan-in 8).
// tid = r*8 + q: r = gate*32+jl (128 gate-rows), q = K-eighth (32 floats).
// Per-thread weights: 8 float4 = 32 VGPR, loaded once -- total working set
// ~57 VGPR fits UNDER the allocator's 64-VGPR/8-wave budget, so residency
// is free (R10/R11/R13 proved 64-VGPR arrays get remat'd in 16-wave blocks).
// Poll: tid<256 polls batch b's 256 hpair words (R9-proven 1 poller/word,
// tag s), writes h into s_h2[8][36] (+4 pad: per-q broadcast addrs land on
// 8 distinct bank-quads -> conflict-free). Matvec: 8 b128 LDS reads + 32
// FMA; K-reduce = 3 shfl_xor (q in lane-low-bits); q==0 lanes write
// s_gates. 2 barriers/step (bar2 fences s_h2/s_gates reuse, R9 scheme).
// Combine: tid<32 owns (b, j=c*32+tid); fast __expf/v_rcp gates.
__global__ __launch_bounds__(1024) void lstm_kernel(
    const float* __restrict__ xg, const float* __restrict__ w_hh,
    float* __restrict__ hs, unsigned long long* __restrict__ hpair)
{
  const int b = blockIdx.x & 15;
  const int c = blockIdx.x >> 4;        // j-chunk 0..7
  const int tid = threadIdx.x;
  const int r = tid >> 3;               // 0..127 = gate*32 + jl
  const int q = tid & 7;                // K-eighth
  const int gate = r >> 5;
  const int jl = r & 31;
  const int j = c * 32 + jl;            // global column 0..255

  // per-thread weights: row gate*256+j, K-chunk [q*32, q*32+32) -- 32 VGPR.
  float4 wv[8];
  {
    const float4* wrow = (const float4*)(w_hh + ((size_t)(gate * 256 + j)) * 256 + q * 32);
    #pragma unroll
    for (int k = 0; k < 8; ++k) wv[k] = wrow[k];
  }
  #pragma unroll
  for (int k = 0; k < 8; ++k)
    asm volatile("" : "+v"(wv[k].x), "+v"(wv[k].y), "+v"(wv[k].z), "+v"(wv[k].w));

  __shared__ float s_h2[8][36];          // [q][k], +4 pad -> distinct bank-quads
  __shared__ float s_gates[4][33];       // [gate][jl]
  float c_reg = 0.f;

  for (int s = 0; s < 64; ++s) {
    float xv = 0.f;
    if (q == 0) xv = xg[(size_t)(s * 16 + b) * 1024 + gate * 256 + j];
    float gv = 0.f;
    if (s > 0) {
      if (tid < 256) {
        const unsigned long long* src = hpair + ((size_t)(s - 1) * 16 + b) * 256 + tid;
        unsigned long long pv;
        do {
          pv = __hip_atomic_load(src, __ATOMIC_RELAXED, __HIP_MEMORY_SCOPE_AGENT);
        } while ((unsigned int)(pv >> 32) != (unsigned int)s);
        s_h2[tid >> 5][tid & 31] = __uint_as_float((unsigned int)pv);
      }
      __syncthreads();
      const float4* hp = (const float4*)&s_h2[q][0];
      float p = 0.f;
      #pragma unroll
      for (int k = 0; k < 8; ++k) {
        float4 h4 = hp[k];
        p = fmaf(h4.x, wv[k].x, p);
        p = fmaf(h4.y, wv[k].y, p);
        p = fmaf(h4.z, wv[k].z, p);
        p = fmaf(h4.w, wv[k].w, p);
      }
      p += __shfl_xor(p, 1);
      p += __shfl_xor(p, 2);
      p += __shfl_xor(p, 4);
      gv = p;
    } else {
      __syncthreads();   // keep barrier count uniform (all threads reach it)
    }
    if (q == 0) s_gates[gate][jl] = gv + xv;
    __syncthreads();
    if (tid < 32) {
      float gi = s_gates[0][tid], gf = s_gates[1][tid];
      float gg = s_gates[2][tid], go = s_gates[3][tid];
      float cn = fsig_(gf) * c_reg + fsig_(gi) * ftanh_(gg);
      c_reg = cn;
      float hv = fsig_(go) * ftanh_(cn);
      hs[(size_t)s * 4096 + b * 256 + j - jl + tid] = hv;   // j-jl+tid == c*32+tid
      unsigned long long pv =
          ((unsigned long long)(unsigned int)(s + 1) << 32) | __float_as_uint(hv);
      __hip_atomic_store(hpair + ((size_t)s * 16 + b) * 256 + c * 32 + tid, pv,
                         __ATOMIC_RELAXED, __HIP_MEMORY_SCOPE_AGENT);
    }
  }
}

// ---------------- classifier head ----------------
__global__ __launch_bounds__(64) void cls_kernel(
    const float* __restrict__ hs, const float* __restrict__ cw,
    const float* __restrict__ cb, float* __restrict__ out)
{
  const int id = blockIdx.x;
  const int b = id / 53;
  const int t = id % 53;
  const int s = 11 + t;
  const int lane = threadIdx.x;
  float4 hv = ((const float4*)(hs + (size_t)s * 4096 + b * 256))[lane];
  float4 wv = ((const float4*)cw)[lane];
  float p = hv.x * wv.x + hv.y * wv.y + hv.z * wv.z + hv.w * wv.w;
  #pragma unroll
  for (int off = 32; off >= 1; off >>= 1) p += __shfl_xor(p, off);
  if (lane == 0) out[id] = tanhf(p + cb[0]);
}

// ---------------------------------------------------------------------------
extern "C" void kernel_launch(void* const* d_in, const int* in_sizes, int n_in,
                              void* d_out, int out_size, void* d_ws, size_t ws_size,
                              hipStream_t stream)
{
  (void)in_sizes; (void)n_in; (void)out_size; (void)ws_size;
  const float* imgs = (const float*)d_in[0];
  const float* w_ih  = (const float*)d_in[31];
  const float* w_hh  = (const float*)d_in[32];
  const float* b_ih  = (const float*)d_in[33];
  const float* b_hh  = (const float*)d_in[34];
  const float* cls_w = (const float*)d_in[35];
  const float* cls_b = (const float*)d_in[36];
  float* out = (float*)d_out;

  float* ws   = (float*)d_ws;
  float* actA = ws;
  float* actB = actA + 16777216;
  float* xg   = actB + 16777216;
  float* hs   = xg + 1048576;
  unsigned long long* hpair = (unsigned long long*)(hs + 262144);
  float* wfp  = hs + 262144 + 524288;
  static const int ocs[6] = {16, 16, 32, 32, 64, 64};
  static const int ics[6] = {3, 16, 16, 32, 32, 64};
  float* wf[6];
  size_t off = 0;
  for (int i = 0; i < 6; ++i) { wf[i] = wfp + off; off += (size_t)ocs[i] * ics[i] * 12; }
  float* biasp = wfp + off;
  float* bias[6];
  for (int i = 0; i < 6; ++i) bias[i] = biasp + i * 64;

  // packed MFMA weights (L1..L5): sizes MT*KG*512 ushorts per plane
  static const int psz[5] = {2560, 5120, 9216, 18432, 36864};
  unsigned short* WH = (unsigned short*)(biasp + 6 * 64);
  unsigned short* WL = WH + 72192;
  unsigned short *wh[5], *wl[5];
  {
    int o = 0;
    for (int i = 0; i < 5; ++i) { wh[i] = WH + o; wl[i] = WL + o; o += psz[i]; }
  }

  float* partials = actA;       // reused post-conv
  unsigned short* Ah = (unsigned short*)(actA + 8388608);
  unsigned short* Al = Ah + 4194304;
  unsigned short* Bh = Al + 4194304;
  unsigned short* Bl = Bh + 4194304;

  FoldPack fp;
  for (int i = 0; i < 6; ++i) {
    fp.w[i] = (const float*)d_in[1 + 5*i];
    fp.g[i] = (const float*)d_in[2 + 5*i];
    fp.b[i] = (const float*)d_in[3 + 5*i];
    fp.m[i] = (const float*)d_in[4 + 5*i];
    fp.v[i] = (const float*)d_in[5 + 5*i];
    fp.wf[i] = wf[i];
    fp.bias[i] = bias[i];
    fp.oc[i] = ocs[i];
    fp.ic[i] = ics[i];
  }
  fold_all<<<dim3(8, 6), 256, 0, stream>>>(fp);

  PackPack pp;
  static const int kgs[5] = {5, 5, 9, 9, 18};
  static const int krs[5] = {144, 144, 288, 288, 576};
  for (int i = 0; i < 5; ++i) {
    pp.w[i] = (const float*)d_in[1 + 5*(i+1)];
    pp.g[i] = (const float*)d_in[2 + 5*(i+1)];
    pp.v[i] = (const float*)d_in[5 + 5*(i+1)];
    pp.wh[i] = wh[i];
    pp.wl[i] = wl[i];
    pp.ic[i] = ics[i+1];
    pp.oc[i] = ocs[i+1];
    pp.kg[i] = kgs[i];
    pp.kreal[i] = krs[i];
  }
  pack_w<<<dim3(36, 5), 256, 0, stream>>>(pp);

  // L0 fp32 direct conv
  conv_bn_relu<3, 16, 64, 64, 2, 4, 2, 1, 4><<<2048, 256, 0, stream>>>(imgs, wf[0], bias[0], actA);
  //            IC  OC  IH  IW  S SPL KG ZR
  conv_mfma<16, 16, 32, 32, 1, 4, 5, 1><<<4096, 256, 0, stream>>>(actA, wh[0], wl[0], bias[1], actB);
  conv_mfma<16, 32, 32, 32, 2, 4, 5, 1><<<4096, 256, 0, stream>>>(actB, wh[1], wl[1], bias[2], actA);
  conv_mfma<32, 32, 16, 16, 1, 1, 9, 0><<<1024, 256, 0, stream>>>(actA, wh[2], wl[2], bias[3], actB);
  conv_mfma<32, 64, 16, 16, 2, 1, 9, 0><<<1024, 256, 0, stream>>>(actB, wh[3], wl[3], bias[4], actA);
  conv_mfma<64, 64,  8,  8, 1, 1, 18, 0><<<1024, 256, 0, stream>>>(actA, wh[4], wl[4], bias[5], actB);

  split_a<<<4096, 256, 0, stream>>>(actB, Ah, Al);
  split_b<<<4096, 256, 0, stream>>>(w_ih, Bh, Bl);
  mfma_xg<<<dim3(8, 8, 8), 256, 0, stream>>>(Ah, Al, Bh, Bl, partials);
  reduce_xg<<<1024, 256, 0, stream>>>(partials, b_ih, b_hh, xg);
  lstm_kernel<<<128, 1024, 0, stream>>>(xg, w_hh, hs, hpair);
  cls_kernel<<<848, 64, 0, stream>>>(hs, cls_w, cls_b, out);
}